// Round 2
// baseline (1205.227 us; speedup 1.0000x reference)
//
#include <hip/hip_runtime.h>
#include <math.h>
#include <float.h>

constexpr int B  = 4;
constexpr int N  = 3072;
constexpr int C  = 512;
constexpr int CL = 768;

// ---------------- JAX threefry2x32 (exact) ----------------
__device__ __forceinline__ unsigned rotl32(unsigned v, int d) { return (v << d) | (v >> (32 - d)); }

__device__ inline void threefry2x32(unsigned k0, unsigned k1, unsigned c0, unsigned c1,
                                    unsigned& o0, unsigned& o1) {
  unsigned ks0 = k0, ks1 = k1, ks2 = 0x1BD11BDAu ^ k0 ^ k1;
  unsigned x0 = c0 + ks0, x1 = c1 + ks1;
#define TF_RND(r) { x0 += x1; x1 = rotl32(x1, (r)); x1 ^= x0; }
  TF_RND(13) TF_RND(15) TF_RND(26) TF_RND(6)  x0 += ks1; x1 += ks2 + 1u;
  TF_RND(17) TF_RND(29) TF_RND(16) TF_RND(24) x0 += ks2; x1 += ks0 + 2u;
  TF_RND(13) TF_RND(15) TF_RND(26) TF_RND(6)  x0 += ks0; x1 += ks1 + 3u;
  TF_RND(17) TF_RND(29) TF_RND(16) TF_RND(24) x0 += ks1; x1 += ks2 + 4u;
  TF_RND(13) TF_RND(15) TF_RND(26) TF_RND(6)  x0 += ks2; x1 += ks0 + 5u;
#undef TF_RND
  o0 = x0; o1 = x1;
}

__device__ inline float jax_uniform_bn(int f) {
  constexpr int HALF = (B * N) / 2;
  unsigned o0, o1, bits;
  if (f < HALF) { threefry2x32(0u, 42u, (unsigned)f, (unsigned)(f + HALF), o0, o1); bits = o0; }
  else          { threefry2x32(0u, 42u, (unsigned)(f - HALF), (unsigned)f, o0, o1); bits = o1; }
  return __uint_as_float((bits >> 9) | 0x3f800000u) - 1.0f;
}

// ---------------- init: counts, distmax, packed assign keys ----------------
__global__ void k_init(int* counts, unsigned* distmax, unsigned long long* packed) {
  int g = blockIdx.x * 256 + threadIdx.x;        // grid covers B*N
  packed[g] = ~0ull;
  if (g < B * CL) counts[g] = 0;
  if (g < B) distmax[g] = 0u;
}

// sq[row] = sum_c x[row,c]^2 ; one wave per row
__global__ __launch_bounds__(64) void k_sq(const float* __restrict__ x, float* __restrict__ sq) {
  int row = blockIdx.x;
  int lane = threadIdx.x;
  const float* xr = x + (size_t)row * C;
  float s = 0.f;
  for (int c = lane * 4; c < C; c += 256) {
    float4 v = *(const float4*)(xr + c);
    s += v.x * v.x + v.y * v.y + v.z * v.z + v.w * v.w;
  }
  for (int o = 32; o > 0; o >>= 1) s += __shfl_down(s, o, 64);
  if (lane == 0) sq[row] = s;
}

// ---------------- dist: 128x256 tile, 8x16 micro, BK=16 ----------------
// Row tiles: 24 (128 rows). Col tiles: 12 (256 cols). Include tile iff ti <= 2*tj+1.
// Full mirror iff ti <= 2*tj-1 (tile strictly above diagonal). Straddle tiles
// (ti = 2tj, 2tj+1) need no mirror: their sub-diagonal mirror images fall inside
// straddle tiles' own direct writes (values are bitwise symmetric).
constexpr int NTILE2 = 156;  // sum_{tj=0..10}(2tj+2) + 24

__global__ __launch_bounds__(256, 2) void k_dist2(const float* __restrict__ x,
                                                  const float* __restrict__ sq,
                                                  float* __restrict__ distbuf, int b0) {
  constexpr int TM = 128, TN = 256, BK = 16;
  constexpr int ASTR = TM + 4;   // 132: +4 pad => k-rows stagger 4 banks
  constexpr int BSTR = TN + 4;   // 260
  __shared__ float As[BK * ASTR];
  __shared__ float Bs[BK * BSTR];

  int bl = blockIdx.y, b = b0 + bl;
  int idx = blockIdx.x;
  int tj = 0;
  for (;;) { int cnt = 2 * tj + 2; if (cnt > 24) cnt = 24; if (idx < cnt) break; idx -= cnt; ++tj; }
  int ti = idx;
  int i0 = ti * TM, j0 = tj * TN;
  bool do_mirror = (ti <= 2 * tj - 1);

  const float* xb  = x + (size_t)b * N * C;
  const float* sqb = sq + (size_t)b * N;
  float* dist = distbuf + (size_t)bl * N * N;

  int tid = threadIdx.x;
  int tx = tid & 15, ty = tid >> 4;

  // staging: thread t loads float4 at (row = base + t>>2, k = (t&3)*4)
  int srow = tid >> 2;           // 0..63
  int skq  = (tid & 3) * 4;      // 0,4,8,12
  const float* gA0 = xb + (size_t)(i0 + srow) * C + skq;
  const float* gA1 = xb + (size_t)(i0 + srow + 64) * C + skq;
  const float* gB[4];
  int swcol[4];
#pragma unroll
  for (int it = 0; it < 4; ++it) {
    int col = it * 64 + srow;
    gB[it] = xb + (size_t)(j0 + col) * C + skq;
    int q = col >> 2;
    swcol[it] = (q ^ ((q >> 3) & 3)) * 4 + (col & 3);  // XOR-swizzled quad
  }
  float* wA0 = &As[skq * ASTR + srow];
  float* wA1 = wA0 + 64;

  // B-fragment read offsets (swizzled quads for cols tx*16 + c*4)
  int boff[4];
#pragma unroll
  for (int c = 0; c < 4; ++c) {
    int q = tx * 4 + c;
    boff[c] = (q ^ ((q >> 3) & 3)) * 4;
  }

  float acc[8][16];
#pragma unroll
  for (int r = 0; r < 8; ++r)
#pragma unroll
    for (int c = 0; c < 16; ++c) acc[r][c] = 0.f;

  float4 pa0 = *(const float4*)gA0;
  float4 pa1 = *(const float4*)gA1;
  float4 pb[4];
#pragma unroll
  for (int it = 0; it < 4; ++it) pb[it] = *(const float4*)gB[it];

  for (int k0 = 0; k0 < C; k0 += BK) {
    __syncthreads();  // prior iteration's LDS reads complete
    wA0[0] = pa0.x; wA0[ASTR] = pa0.y; wA0[2 * ASTR] = pa0.z; wA0[3 * ASTR] = pa0.w;
    wA1[0] = pa1.x; wA1[ASTR] = pa1.y; wA1[2 * ASTR] = pa1.z; wA1[3 * ASTR] = pa1.w;
#pragma unroll
    for (int it = 0; it < 4; ++it) {
      float* wB = &Bs[skq * BSTR + swcol[it]];
      wB[0] = pb[it].x; wB[BSTR] = pb[it].y; wB[2 * BSTR] = pb[it].z; wB[3 * BSTR] = pb[it].w;
    }
    __syncthreads();  // LDS tile visible
    int kn = k0 + BK;
    if (kn < C) {     // prefetch next slice; overlaps with the MFMA... FMA burst below
      pa0 = *(const float4*)(gA0 + kn);
      pa1 = *(const float4*)(gA1 + kn);
#pragma unroll
      for (int it = 0; it < 4; ++it) pb[it] = *(const float4*)(gB[it] + kn);
    }
#pragma unroll
    for (int kk = 0; kk < BK; ++kk) {
      const float* ar = &As[kk * ASTR + ty * 8];
      float a[8];
      *(float4*)&a[0] = *(const float4*)ar;
      *(float4*)&a[4] = *(const float4*)(ar + 4);
      const float* br = &Bs[kk * BSTR];
      float bb[16];
      *(float4*)&bb[0]  = *(const float4*)(br + boff[0]);
      *(float4*)&bb[4]  = *(const float4*)(br + boff[1]);
      *(float4*)&bb[8]  = *(const float4*)(br + boff[2]);
      *(float4*)&bb[12] = *(const float4*)(br + boff[3]);
#pragma unroll
      for (int r = 0; r < 8; ++r)
#pragma unroll
        for (int c = 0; c < 16; ++c)
          acc[r][c] = fmaf(a[r], bb[c], acc[r][c]);
    }
  }

  const float SQC = 22.627416997969522f;
  float sqi[8], sqj[16];
#pragma unroll
  for (int r = 0; r < 8; ++r) sqi[r] = sqb[i0 + ty * 8 + r];
#pragma unroll
  for (int c = 0; c < 16; ++c) sqj[c] = sqb[j0 + tx * 16 + c];
#pragma unroll
  for (int r = 0; r < 8; ++r)
#pragma unroll
    for (int c = 0; c < 16; ++c) {
      float d2 = fmaxf(sqi[r] + sqj[c] - 2.0f * acc[r][c], 0.0f);
      acc[r][c] = sqrtf(d2) / SQC;   // division: bitwise-match reference path
    }

#pragma unroll
  for (int r = 0; r < 8; ++r) {
    float* drow = dist + (size_t)(i0 + ty * 8 + r) * N + j0 + tx * 16;
#pragma unroll
    for (int c4 = 0; c4 < 4; ++c4)
      *(float4*)(drow + c4 * 4) =
        make_float4(acc[r][c4 * 4], acc[r][c4 * 4 + 1], acc[r][c4 * 4 + 2], acc[r][c4 * 4 + 3]);
  }
  if (do_mirror) {
#pragma unroll
    for (int c = 0; c < 16; ++c) {
      float* dcol = dist + (size_t)(j0 + tx * 16 + c) * N + i0 + ty * 8;
      *(float4*)dcol       = make_float4(acc[0][c], acc[1][c], acc[2][c], acc[3][c]);
      *(float4*)(dcol + 4) = make_float4(acc[4][c], acc[5][c], acc[6][c], acc[7][c]);
    }
  }
}

// ---------------- 5-NN density ----------------
__device__ __forceinline__ void ins5(float* t, float v) {
  if (v < t[4]) {
    t[4] = v;
#pragma unroll
    for (int q = 4; q > 0; --q)
      if (t[q] < t[q - 1]) { float tmp = t[q]; t[q] = t[q - 1]; t[q - 1] = tmp; }
  }
}

__global__ __launch_bounds__(256) void k_knn(const float* __restrict__ distbuf,
                                             float* __restrict__ density,
                                             unsigned* __restrict__ distmax, int b0) {
  int i = blockIdx.x, bl = blockIdx.y, b = b0 + bl;
  int tid = threadIdx.x;
  const float* row = distbuf + ((size_t)bl * N + i) * N;

  float t5[5] = {FLT_MAX, FLT_MAX, FLT_MAX, FLT_MAX, FLT_MAX};
  float mx = 0.f;
  for (int j = tid * 4; j < N; j += 1024) {
    float4 v = *(const float4*)(row + j);
    mx = fmaxf(mx, fmaxf(fmaxf(v.x, v.y), fmaxf(v.z, v.w)));
    ins5(t5, v.x); ins5(t5, v.y); ins5(t5, v.z); ins5(t5, v.w);
  }
  for (int off = 32; off > 0; off >>= 1) {
    mx = fmaxf(mx, __shfl_down(mx, off, 64));
    float o0 = __shfl_down(t5[0], off, 64);
    float o1 = __shfl_down(t5[1], off, 64);
    float o2 = __shfl_down(t5[2], off, 64);
    float o3 = __shfl_down(t5[3], off, 64);
    float o4 = __shfl_down(t5[4], off, 64);
    ins5(t5, o0); ins5(t5, o1); ins5(t5, o2); ins5(t5, o3); ins5(t5, o4);
  }
  __shared__ float s5[4][5];
  __shared__ float smx[4];
  int wv = tid >> 6, ln = tid & 63;
  if (ln == 0) {
#pragma unroll
    for (int q = 0; q < 5; ++q) s5[wv][q] = t5[q];
    smx[wv] = mx;
  }
  __syncthreads();
  if (tid == 0) {
    for (int w = 1; w < 4; ++w) {
#pragma unroll
      for (int q = 0; q < 5; ++q) ins5(t5, s5[w][q]);
      mx = fmaxf(mx, smx[w]);
    }
    float sum = 0.f;
#pragma unroll
    for (int q = 0; q < 5; ++q) sum += t5[q] * t5[q];
    float dens = expf(-(sum / 5.0f)) + jax_uniform_bn(b * N + i) * 1e-6f;
    density[b * N + i] = dens;
    atomicMax(&distmax[b], __float_as_uint(mx));
  }
}

// ---------------- masked min -> score ----------------
__global__ __launch_bounds__(256) void k_maskmin(const float* __restrict__ distbuf,
                                                 const float* __restrict__ density,
                                                 const unsigned* __restrict__ distmax,
                                                 float* __restrict__ score, int b0) {
  __shared__ float sd[N];
  __shared__ float red[4];
  int i = blockIdx.x, bl = blockIdx.y, b = b0 + bl;
  int tid = threadIdx.x;
  const float* db = density + (size_t)b * N;
  for (int j = tid * 4; j < N; j += 1024) *(float4*)(sd + j) = *(const float4*)(db + j);
  __syncthreads();
  float di = sd[i];
  float dmax = __uint_as_float(distmax[b]);
  const float* row = distbuf + ((size_t)bl * N + i) * N;
  float mn = dmax;
  for (int j = tid * 4; j < N; j += 1024) {
    float4 v = *(const float4*)(row + j);
    float4 d = *(const float4*)(sd + j);
    if (d.x > di) mn = fminf(mn, v.x);
    if (d.y > di) mn = fminf(mn, v.y);
    if (d.z > di) mn = fminf(mn, v.z);
    if (d.w > di) mn = fminf(mn, v.w);
  }
  for (int off = 32; off > 0; off >>= 1) mn = fminf(mn, __shfl_down(mn, off, 64));
  if ((tid & 63) == 0) red[tid >> 6] = mn;
  __syncthreads();
  if (tid == 0) score[b * N + i] = fminf(fminf(red[0], red[1]), fminf(red[2], red[3])) * di;
}

// ---------------- top-CL sorted selection: bitonic over 4096, 1024 threads ----------------
__global__ __launch_bounds__(1024) void k_sort(const float* __restrict__ score,
                                               int* __restrict__ index_down, int b0) {
  __shared__ float ss[4096];
  __shared__ int   si[4096];
  int b = b0 + blockIdx.x;
  int tid = threadIdx.x;
  for (int p = tid; p < 4096; p += 1024) {
    if (p < N) { ss[p] = score[b * N + p]; si[p] = p; }
    else       { ss[p] = -INFINITY; si[p] = 0x7fffffff; }
  }
  __syncthreads();
  for (int k = 2; k <= 4096; k <<= 1) {
    for (int j = k >> 1; j > 0; j >>= 1) {
      for (int p = tid; p < 4096; p += 1024) {
        int q = p ^ j;
        if (q > p) {
          float s1 = ss[p], s2 = ss[q];
          int i1 = si[p], i2 = si[q];
          bool up = ((p & k) == 0);
          bool inOrder = (s1 > s2) || (s1 == s2 && i1 < i2);
          if (inOrder != up) { ss[p] = s2; ss[q] = s1; si[p] = i2; si[q] = i1; }
        }
      }
      __syncthreads();
    }
  }
  for (int r = tid; r < CL; r += 1024) index_down[b * CL + r] = si[r];
}

// ---------------- assignment: chunked rows + packed (dist,idx) atomicMin ----------------
__global__ __launch_bounds__(256) void k_assign_part(const float* __restrict__ distbuf,
                                                     const int* __restrict__ index_down,
                                                     unsigned long long* __restrict__ packed, int b0) {
  constexpr int RCH = CL / 8;  // 96
  __shared__ int sid[RCH];
  int bl = blockIdx.z, b = b0 + bl;
  int r0 = blockIdx.y * RCH;
  int tid = threadIdx.x;
  for (int r = tid; r < RCH; r += 256) sid[r] = index_down[b * CL + r0 + r];
  __syncthreads();
  int j = blockIdx.x * 256 + tid;
  const float* base = distbuf + (size_t)bl * N * N;
  float best = FLT_MAX; int bestr = 0;
#pragma unroll 8
  for (int r = 0; r < RCH; ++r) {
    float d = base[(size_t)sid[r] * N + j];
    if (d < best) { best = d; bestr = r0 + r; }  // strict < => first-min within chunk
  }
  unsigned long long key = ((unsigned long long)__float_as_uint(best) << 32) | (unsigned)bestr;
  atomicMin(&packed[b * N + j], key);  // dist>=0: bits monotone; ties -> smaller r
}

__global__ void k_assign_fin(const unsigned long long* __restrict__ packed,
                             int* __restrict__ idx_cluster) {
  int g = blockIdx.x * 256 + threadIdx.x;
  idx_cluster[g] = (int)(unsigned)(packed[g] & 0xffffffffull);
}

__global__ void k_override(const int* __restrict__ index_down, int* __restrict__ idx_cluster) {
  int b = blockIdx.x;
  int r = threadIdx.x;  // CL threads
  idx_cluster[b * N + index_down[b * CL + r]] = r;
}

// ---------------- merge ----------------
__global__ void k_count(const int* __restrict__ idx_cluster, int* __restrict__ counts) {
  int g = blockIdx.x * 256 + threadIdx.x;
  int b = g / N;
  atomicAdd(&counts[b * CL + idx_cluster[g]], 1);
}

__global__ __launch_bounds__(1024) void k_scan(const int* __restrict__ counts,
                                               int* __restrict__ offsets, int* __restrict__ cursor) {
  constexpr int T = B * CL;  // 3072
  __shared__ int sm[T];
  int tid = threadIdx.x;
  for (int p = tid; p < T; p += 1024) sm[p] = counts[p];
  __syncthreads();
  for (int off = 1; off < T; off <<= 1) {
    int v[3]; int n = 0;
    for (int p = tid; p < T; p += 1024) { v[n++] = (p >= off) ? sm[p - off] : 0; }
    __syncthreads();
    n = 0;
    for (int p = tid; p < T; p += 1024) { sm[p] += v[n++]; }
    __syncthreads();
  }
  for (int p = tid; p < T; p += 1024) {
    int e = sm[p] - counts[p];
    offsets[p] = e; cursor[p] = e;
  }
}

__global__ void k_fill(const int* __restrict__ idx_cluster, int* __restrict__ cursor,
                       int* __restrict__ members) {
  int g = blockIdx.x * 256 + threadIdx.x;
  int b = g / N, i = g % N;
  int seg = b * CL + idx_cluster[g];
  int pos = atomicAdd(&cursor[seg], 1);
  members[pos] = i;
}

__global__ __launch_bounds__(128) void k_gather(const float* __restrict__ x, const int* __restrict__ members,
                                                const int* __restrict__ offsets, const int* __restrict__ counts,
                                                float* __restrict__ out0) {
  int seg = blockIdx.x;
  int b = seg / CL;
  int cnt = counts[seg], off = offsets[seg];
  float nw = 1.0f / ((float)cnt + 1e-6f);
  int c = threadIdx.x * 4;
  const float* xb = x + (size_t)b * N * C;
  float4 acc = make_float4(0.f, 0.f, 0.f, 0.f);
  for (int m = 0; m < cnt; ++m) {
    int tok = members[off + m];
    float4 v = *(const float4*)(xb + (size_t)tok * C + c);
    acc.x += v.x * nw; acc.y += v.y * nw; acc.z += v.z * nw; acc.w += v.w * nw;
  }
  *(float4*)(out0 + (size_t)seg * C + c) = acc;
}

__global__ void k_final(const float* __restrict__ agg_weight, const int* __restrict__ idx_token,
                        const int* __restrict__ idx_cluster, const int* __restrict__ counts,
                        float* __restrict__ out1, float* __restrict__ out2, float* __restrict__ out3) {
  int g = blockIdx.x * 256 + threadIdx.x;
  int b = g / N;
  int it = idx_token[g];
  int clt = idx_cluster[b * N + it];
  float nwt = 1.0f / ((float)counts[b * CL + clt] + 1e-6f);
  out1[g] = agg_weight[g] * nwt;
  out2[g] = (float)clt;
  out3[g] = (float)idx_cluster[g];
}

// ---------------- launch ----------------
extern "C" void kernel_launch(void* const* d_in, const int* in_sizes, int n_in,
                              void* d_out, int out_size, void* d_ws, size_t ws_size,
                              hipStream_t stream) {
  const float* x          = (const float*)d_in[0];
  const int*   idx_token  = (const int*)d_in[1];
  const float* agg_weight = (const float*)d_in[2];

  float* out0 = (float*)d_out;
  float* out1 = out0 + (size_t)B * CL * C;
  float* out2 = out1 + (size_t)B * N;
  float* out3 = out2 + (size_t)B * N;

  char* w = (char*)d_ws;
  auto carve = [&](size_t bytes) { char* p = w; w += (bytes + 255) & ~(size_t)255; return p; };
  float*    sq         = (float*)carve((size_t)B * N * 4);
  float*    density    = (float*)carve((size_t)B * N * 4);
  float*    score      = (float*)carve((size_t)B * N * 4);
  unsigned* distmax    = (unsigned*)carve((size_t)B * 4);
  int*      index_down = (int*)carve((size_t)B * CL * 4);
  int*      idx_clus   = (int*)carve((size_t)B * N * 4);
  int*      counts     = (int*)carve((size_t)B * CL * 4);
  int*      offsets    = (int*)carve((size_t)B * CL * 4);
  int*      cursor     = (int*)carve((size_t)B * CL * 4);
  int*      members    = (int*)carve((size_t)B * N * 4);
  unsigned long long* packed = (unsigned long long*)carve((size_t)B * N * 8);
  size_t used = (size_t)(w - (char*)d_ws);
  size_t per  = (size_t)N * N * 4;
  int nb_max = (ws_size > used) ? (int)((ws_size - used) / per) : 0;
  if (nb_max < 1) nb_max = 1;
  if (nb_max > B) nb_max = B;
  float* distbuf = (float*)w;

  k_init<<<(B * N) / 256, 256, 0, stream>>>(counts, distmax, packed);
  k_sq<<<B * N, 64, 0, stream>>>(x, sq);

  for (int b0 = 0; b0 < B; b0 += nb_max) {
    int nb = (B - b0 < nb_max) ? (B - b0) : nb_max;
    k_dist2<<<dim3(NTILE2, nb), 256, 0, stream>>>(x, sq, distbuf, b0);
    k_knn<<<dim3(N, nb), 256, 0, stream>>>(distbuf, density, distmax, b0);
    k_maskmin<<<dim3(N, nb), 256, 0, stream>>>(distbuf, density, distmax, score, b0);
    k_sort<<<nb, 1024, 0, stream>>>(score, index_down, b0);
    k_assign_part<<<dim3(N / 256, 8, nb), 256, 0, stream>>>(distbuf, index_down, packed, b0);
  }

  k_assign_fin<<<(B * N) / 256, 256, 0, stream>>>(packed, idx_clus);
  k_override<<<B, CL, 0, stream>>>(index_down, idx_clus);
  k_count<<<(B * N) / 256, 256, 0, stream>>>(idx_clus, counts);
  k_scan<<<1, 1024, 0, stream>>>(counts, offsets, cursor);
  k_fill<<<(B * N) / 256, 256, 0, stream>>>(idx_clus, cursor, members);
  k_gather<<<B * CL, 128, 0, stream>>>(x, members, offsets, counts, out0);
  k_final<<<(B * N) / 256, 256, 0, stream>>>(agg_weight, idx_token, idx_clus, counts, out1, out2, out3);
}

// Round 3
// 678.209 us; speedup vs baseline: 1.7771x; 1.7771x over previous
//
#include <hip/hip_runtime.h>
#include <math.h>
#include <float.h>

constexpr int B  = 4;
constexpr int N  = 3072;
constexpr int C  = 512;
constexpr int CL = 768;

// ---------------- JAX threefry2x32 (exact) ----------------
__device__ __forceinline__ unsigned rotl32(unsigned v, int d) { return (v << d) | (v >> (32 - d)); }

__device__ inline void threefry2x32(unsigned k0, unsigned k1, unsigned c0, unsigned c1,
                                    unsigned& o0, unsigned& o1) {
  unsigned ks0 = k0, ks1 = k1, ks2 = 0x1BD11BDAu ^ k0 ^ k1;
  unsigned x0 = c0 + ks0, x1 = c1 + ks1;
#define TF_RND(r) { x0 += x1; x1 = rotl32(x1, (r)); x1 ^= x0; }
  TF_RND(13) TF_RND(15) TF_RND(26) TF_RND(6)  x0 += ks1; x1 += ks2 + 1u;
  TF_RND(17) TF_RND(29) TF_RND(16) TF_RND(24) x0 += ks2; x1 += ks0 + 2u;
  TF_RND(13) TF_RND(15) TF_RND(26) TF_RND(6)  x0 += ks0; x1 += ks1 + 3u;
  TF_RND(17) TF_RND(29) TF_RND(16) TF_RND(24) x0 += ks1; x1 += ks2 + 4u;
  TF_RND(13) TF_RND(15) TF_RND(26) TF_RND(6)  x0 += ks2; x1 += ks0 + 5u;
#undef TF_RND
  o0 = x0; o1 = x1;
}

__device__ inline float jax_uniform_bn(int f) {
  constexpr int HALF = (B * N) / 2;
  unsigned o0, o1, bits;
  if (f < HALF) { threefry2x32(0u, 42u, (unsigned)f, (unsigned)(f + HALF), o0, o1); bits = o0; }
  else          { threefry2x32(0u, 42u, (unsigned)(f - HALF), (unsigned)f, o0, o1); bits = o1; }
  return __uint_as_float((bits >> 9) | 0x3f800000u) - 1.0f;
}

// ---------------- init ----------------
__global__ void k_init(int* counts, unsigned* distmax, unsigned long long* packed) {
  int g = blockIdx.x * 256 + threadIdx.x;
  packed[g] = ~0ull;
  if (g < B * CL) counts[g] = 0;
  if (g < B) distmax[g] = 0u;
}

__global__ __launch_bounds__(64) void k_sq(const float* __restrict__ x, float* __restrict__ sq) {
  int row = blockIdx.x;
  int lane = threadIdx.x;
  const float* xr = x + (size_t)row * C;
  float s = 0.f;
  for (int c = lane * 4; c < C; c += 256) {
    float4 v = *(const float4*)(xr + c);
    s += v.x * v.x + v.y * v.y + v.z * v.z + v.w * v.w;
  }
  for (int o = 32; o > 0; o >>= 1) s += __shfl_down(s, o, 64);
  if (lane == 0) sq[row] = s;
}

// ---------------- dist: 128x128 tile, 8x8 micro, BK=16, upper-tri + mirror ----------------
constexpr int NT3 = N / 128;                   // 24
constexpr int NTILE3 = NT3 * (NT3 + 1) / 2;    // 300

__global__ __launch_bounds__(256) void k_dist3(const float* __restrict__ x,
                                               const float* __restrict__ sq,
                                               float* __restrict__ distbuf, int b0) {
  constexpr int BK = 16;
  constexpr int STR = 132;   // 128 + 4 pad
  __shared__ float As[BK * STR];
  __shared__ float Bs[BK * STR];

  int bl = blockIdx.y, b = b0 + bl;
  // map blockIdx.x -> upper-tri (ti <= tj)
  int idx = blockIdx.x;
  int ti = 0, rem = idx;
  while (rem >= NT3 - ti) { rem -= NT3 - ti; ++ti; }
  int tj = ti + rem;
  int i0 = ti * 128, j0 = tj * 128;
  bool do_mirror = (ti != tj);

  const float* xb  = x + (size_t)b * N * C;
  const float* sqb = sq + (size_t)b * N;
  float* dist = distbuf + (size_t)bl * N * N;

  int tid = threadIdx.x;
  int tx = tid & 15, ty = tid >> 4;

  // staging: thread t loads float4 at (row = t>>2 [+64], k = (t&3)*4)
  int srow = tid >> 2;           // 0..63
  int skq  = (tid & 3) * 4;      // 0,4,8,12
  const float* gA0 = xb + (size_t)(i0 + srow) * C + skq;
  const float* gA1 = xb + (size_t)(i0 + srow + 64) * C + skq;
  const float* gB0 = xb + (size_t)(j0 + srow) * C + skq;
  const float* gB1 = xb + (size_t)(j0 + srow + 64) * C + skq;
  float* wA0 = &As[skq * STR + srow];
  float* wA1 = wA0 + 64;
  float* wB0 = &Bs[skq * STR + srow];
  float* wB1 = wB0 + 64;

  float acc[8][8];
#pragma unroll
  for (int r = 0; r < 8; ++r)
#pragma unroll
    for (int c = 0; c < 8; ++c) acc[r][c] = 0.f;

  float4 pa0 = *(const float4*)gA0;
  float4 pa1 = *(const float4*)gA1;
  float4 pb0 = *(const float4*)gB0;
  float4 pb1 = *(const float4*)gB1;

  for (int k0 = 0; k0 < C; k0 += BK) {
    __syncthreads();
    wA0[0] = pa0.x; wA0[STR] = pa0.y; wA0[2 * STR] = pa0.z; wA0[3 * STR] = pa0.w;
    wA1[0] = pa1.x; wA1[STR] = pa1.y; wA1[2 * STR] = pa1.z; wA1[3 * STR] = pa1.w;
    wB0[0] = pb0.x; wB0[STR] = pb0.y; wB0[2 * STR] = pb0.z; wB0[3 * STR] = pb0.w;
    wB1[0] = pb1.x; wB1[STR] = pb1.y; wB1[2 * STR] = pb1.z; wB1[3 * STR] = pb1.w;
    __syncthreads();
    int kn = k0 + BK;
    if (kn < C) {
      pa0 = *(const float4*)(gA0 + kn);
      pa1 = *(const float4*)(gA1 + kn);
      pb0 = *(const float4*)(gB0 + kn);
      pb1 = *(const float4*)(gB1 + kn);
    }
#pragma unroll
    for (int kk = 0; kk < BK; ++kk) {
      float a[8], bb[8];
      const float* ar = &As[kk * STR + ty * 8];
      const float* br = &Bs[kk * STR + tx * 8];
      *(float4*)&a[0]  = *(const float4*)ar;
      *(float4*)&a[4]  = *(const float4*)(ar + 4);
      *(float4*)&bb[0] = *(const float4*)br;
      *(float4*)&bb[4] = *(const float4*)(br + 4);
#pragma unroll
      for (int r = 0; r < 8; ++r)
#pragma unroll
        for (int c = 0; c < 8; ++c)
          acc[r][c] = fmaf(a[r], bb[c], acc[r][c]);
    }
  }

  const float SQC = 22.627416997969522f;
  float sqi[8], sqj[8];
#pragma unroll
  for (int r = 0; r < 8; ++r) sqi[r] = sqb[i0 + ty * 8 + r];
#pragma unroll
  for (int c = 0; c < 8; ++c) sqj[c] = sqb[j0 + tx * 8 + c];
#pragma unroll
  for (int r = 0; r < 8; ++r)
#pragma unroll
    for (int c = 0; c < 8; ++c) {
      float d2 = fmaxf(sqi[r] + sqj[c] - 2.0f * acc[r][c], 0.0f);
      acc[r][c] = sqrtf(d2) / SQC;
    }

#pragma unroll
  for (int r = 0; r < 8; ++r) {
    float* drow = dist + (size_t)(i0 + ty * 8 + r) * N + j0 + tx * 8;
    *(float4*)drow       = make_float4(acc[r][0], acc[r][1], acc[r][2], acc[r][3]);
    *(float4*)(drow + 4) = make_float4(acc[r][4], acc[r][5], acc[r][6], acc[r][7]);
  }
  if (do_mirror) {
#pragma unroll
    for (int c = 0; c < 8; ++c) {
      float* dcol = dist + (size_t)(j0 + tx * 8 + c) * N + i0 + ty * 8;
      *(float4*)dcol       = make_float4(acc[0][c], acc[1][c], acc[2][c], acc[3][c]);
      *(float4*)(dcol + 4) = make_float4(acc[4][c], acc[5][c], acc[6][c], acc[7][c]);
    }
  }
}

// ---------------- 5-NN density ----------------
__device__ __forceinline__ void ins5(float* t, float v) {
  if (v < t[4]) {
    t[4] = v;
#pragma unroll
    for (int q = 4; q > 0; --q)
      if (t[q] < t[q - 1]) { float tmp = t[q]; t[q] = t[q - 1]; t[q - 1] = tmp; }
  }
}

__global__ __launch_bounds__(256) void k_knn(const float* __restrict__ distbuf,
                                             float* __restrict__ density,
                                             unsigned* __restrict__ distmax, int b0) {
  int i = blockIdx.x, bl = blockIdx.y, b = b0 + bl;
  int tid = threadIdx.x;
  const float* row = distbuf + ((size_t)bl * N + i) * N;

  float t5[5] = {FLT_MAX, FLT_MAX, FLT_MAX, FLT_MAX, FLT_MAX};
  float mx = 0.f;
  for (int j = tid * 4; j < N; j += 1024) {
    float4 v = *(const float4*)(row + j);
    mx = fmaxf(mx, fmaxf(fmaxf(v.x, v.y), fmaxf(v.z, v.w)));
    ins5(t5, v.x); ins5(t5, v.y); ins5(t5, v.z); ins5(t5, v.w);
  }
  for (int off = 32; off > 0; off >>= 1) {
    mx = fmaxf(mx, __shfl_down(mx, off, 64));
    float o0 = __shfl_down(t5[0], off, 64);
    float o1 = __shfl_down(t5[1], off, 64);
    float o2 = __shfl_down(t5[2], off, 64);
    float o3 = __shfl_down(t5[3], off, 64);
    float o4 = __shfl_down(t5[4], off, 64);
    ins5(t5, o0); ins5(t5, o1); ins5(t5, o2); ins5(t5, o3); ins5(t5, o4);
  }
  __shared__ float s5[4][5];
  __shared__ float smx[4];
  int wv = tid >> 6, ln = tid & 63;
  if (ln == 0) {
#pragma unroll
    for (int q = 0; q < 5; ++q) s5[wv][q] = t5[q];
    smx[wv] = mx;
  }
  __syncthreads();
  if (tid == 0) {
    for (int w = 1; w < 4; ++w) {
#pragma unroll
      for (int q = 0; q < 5; ++q) ins5(t5, s5[w][q]);
      mx = fmaxf(mx, smx[w]);
    }
    float sum = 0.f;
#pragma unroll
    for (int q = 0; q < 5; ++q) sum += t5[q] * t5[q];
    float dens = expf(-(sum / 5.0f)) + jax_uniform_bn(b * N + i) * 1e-6f;
    density[b * N + i] = dens;
    atomicMax(&distmax[b], __float_as_uint(mx));
  }
}

// ---------------- masked min -> score ----------------
__global__ __launch_bounds__(256) void k_maskmin(const float* __restrict__ distbuf,
                                                 const float* __restrict__ density,
                                                 const unsigned* __restrict__ distmax,
                                                 float* __restrict__ score, int b0) {
  __shared__ float sd[N];
  __shared__ float red[4];
  int i = blockIdx.x, bl = blockIdx.y, b = b0 + bl;
  int tid = threadIdx.x;
  const float* db = density + (size_t)b * N;
  for (int j = tid * 4; j < N; j += 1024) *(float4*)(sd + j) = *(const float4*)(db + j);
  __syncthreads();
  float di = sd[i];
  float dmax = __uint_as_float(distmax[b]);
  const float* row = distbuf + ((size_t)bl * N + i) * N;
  float mn = dmax;
  for (int j = tid * 4; j < N; j += 1024) {
    float4 v = *(const float4*)(row + j);
    float4 d = *(const float4*)(sd + j);
    if (d.x > di) mn = fminf(mn, v.x);
    if (d.y > di) mn = fminf(mn, v.y);
    if (d.z > di) mn = fminf(mn, v.z);
    if (d.w > di) mn = fminf(mn, v.w);
  }
  for (int off = 32; off > 0; off >>= 1) mn = fminf(mn, __shfl_down(mn, off, 64));
  if ((tid & 63) == 0) red[tid >> 6] = mn;
  __syncthreads();
  if (tid == 0) score[b * N + i] = fminf(fminf(red[0], red[1]), fminf(red[2], red[3])) * di;
}

// ---------------- top-CL sorted selection ----------------
__global__ __launch_bounds__(1024) void k_sort(const float* __restrict__ score,
                                               int* __restrict__ index_down, int b0) {
  __shared__ float ss[4096];
  __shared__ int   si[4096];
  int b = b0 + blockIdx.x;
  int tid = threadIdx.x;
  for (int p = tid; p < 4096; p += 1024) {
    if (p < N) { ss[p] = score[b * N + p]; si[p] = p; }
    else       { ss[p] = -INFINITY; si[p] = 0x7fffffff; }
  }
  __syncthreads();
  for (int k = 2; k <= 4096; k <<= 1) {
    for (int j = k >> 1; j > 0; j >>= 1) {
      for (int p = tid; p < 4096; p += 1024) {
        int q = p ^ j;
        if (q > p) {
          float s1 = ss[p], s2 = ss[q];
          int i1 = si[p], i2 = si[q];
          bool up = ((p & k) == 0);
          bool inOrder = (s1 > s2) || (s1 == s2 && i1 < i2);
          if (inOrder != up) { ss[p] = s2; ss[q] = s1; si[p] = i2; si[q] = i1; }
        }
      }
      __syncthreads();
    }
  }
  for (int r = tid; r < CL; r += 1024) index_down[b * CL + r] = si[r];
}

// ---------------- assignment ----------------
__global__ __launch_bounds__(256) void k_assign_part(const float* __restrict__ distbuf,
                                                     const int* __restrict__ index_down,
                                                     unsigned long long* __restrict__ packed, int b0) {
  constexpr int RCH = CL / 8;  // 96
  __shared__ int sid[RCH];
  int bl = blockIdx.z, b = b0 + bl;
  int r0 = blockIdx.y * RCH;
  int tid = threadIdx.x;
  for (int r = tid; r < RCH; r += 256) sid[r] = index_down[b * CL + r0 + r];
  __syncthreads();
  int j = blockIdx.x * 256 + tid;
  const float* base = distbuf + (size_t)bl * N * N;
  float best = FLT_MAX; int bestr = 0;
#pragma unroll 8
  for (int r = 0; r < RCH; ++r) {
    float d = base[(size_t)sid[r] * N + j];
    if (d < best) { best = d; bestr = r0 + r; }
  }
  unsigned long long key = ((unsigned long long)__float_as_uint(best) << 32) | (unsigned)bestr;
  atomicMin(&packed[b * N + j], key);
}

__global__ void k_assign_fin(const unsigned long long* __restrict__ packed,
                             int* __restrict__ idx_cluster) {
  int g = blockIdx.x * 256 + threadIdx.x;
  idx_cluster[g] = (int)(unsigned)(packed[g] & 0xffffffffull);
}

__global__ void k_override(const int* __restrict__ index_down, int* __restrict__ idx_cluster) {
  int b = blockIdx.x;
  int r = threadIdx.x;
  idx_cluster[b * N + index_down[b * CL + r]] = r;
}

// ---------------- merge ----------------
__global__ void k_count(const int* __restrict__ idx_cluster, int* __restrict__ counts) {
  int g = blockIdx.x * 256 + threadIdx.x;
  int b = g / N;
  atomicAdd(&counts[b * CL + idx_cluster[g]], 1);
}

__global__ __launch_bounds__(1024) void k_scan(const int* __restrict__ counts,
                                               int* __restrict__ offsets, int* __restrict__ cursor) {
  constexpr int T = B * CL;
  __shared__ int sm[T];
  int tid = threadIdx.x;
  for (int p = tid; p < T; p += 1024) sm[p] = counts[p];
  __syncthreads();
  for (int off = 1; off < T; off <<= 1) {
    int v[3]; int n = 0;
    for (int p = tid; p < T; p += 1024) { v[n++] = (p >= off) ? sm[p - off] : 0; }
    __syncthreads();
    n = 0;
    for (int p = tid; p < T; p += 1024) { sm[p] += v[n++]; }
    __syncthreads();
  }
  for (int p = tid; p < T; p += 1024) {
    int e = sm[p] - counts[p];
    offsets[p] = e; cursor[p] = e;
  }
}

__global__ void k_fill(const int* __restrict__ idx_cluster, int* __restrict__ cursor,
                       int* __restrict__ members) {
  int g = blockIdx.x * 256 + threadIdx.x;
  int b = g / N, i = g % N;
  int seg = b * CL + idx_cluster[g];
  int pos = atomicAdd(&cursor[seg], 1);
  members[pos] = i;
}

__global__ __launch_bounds__(128) void k_gather(const float* __restrict__ x, const int* __restrict__ members,
                                                const int* __restrict__ offsets, const int* __restrict__ counts,
                                                float* __restrict__ out0) {
  int seg = blockIdx.x;
  int b = seg / CL;
  int cnt = counts[seg], off = offsets[seg];
  float nw = 1.0f / ((float)cnt + 1e-6f);
  int c = threadIdx.x * 4;
  const float* xb = x + (size_t)b * N * C;
  float4 acc = make_float4(0.f, 0.f, 0.f, 0.f);
  for (int m = 0; m < cnt; ++m) {
    int tok = members[off + m];
    float4 v = *(const float4*)(xb + (size_t)tok * C + c);
    acc.x += v.x * nw; acc.y += v.y * nw; acc.z += v.z * nw; acc.w += v.w * nw;
  }
  *(float4*)(out0 + (size_t)seg * C + c) = acc;
}

__global__ void k_final(const float* __restrict__ agg_weight, const int* __restrict__ idx_token,
                        const int* __restrict__ idx_cluster, const int* __restrict__ counts,
                        float* __restrict__ out1, float* __restrict__ out2, float* __restrict__ out3) {
  int g = blockIdx.x * 256 + threadIdx.x;
  int b = g / N;
  int it = idx_token[g];
  int clt = idx_cluster[b * N + it];
  float nwt = 1.0f / ((float)counts[b * CL + clt] + 1e-6f);
  out1[g] = agg_weight[g] * nwt;
  out2[g] = (float)clt;
  out3[g] = (float)idx_cluster[g];
}

// ---------------- launch ----------------
extern "C" void kernel_launch(void* const* d_in, const int* in_sizes, int n_in,
                              void* d_out, int out_size, void* d_ws, size_t ws_size,
                              hipStream_t stream) {
  const float* x          = (const float*)d_in[0];
  const int*   idx_token  = (const int*)d_in[1];
  const float* agg_weight = (const float*)d_in[2];

  float* out0 = (float*)d_out;
  float* out1 = out0 + (size_t)B * CL * C;
  float* out2 = out1 + (size_t)B * N;
  float* out3 = out2 + (size_t)B * N;

  char* w = (char*)d_ws;
  auto carve = [&](size_t bytes) { char* p = w; w += (bytes + 255) & ~(size_t)255; return p; };
  float*    sq         = (float*)carve((size_t)B * N * 4);
  float*    density    = (float*)carve((size_t)B * N * 4);
  float*    score      = (float*)carve((size_t)B * N * 4);
  unsigned* distmax    = (unsigned*)carve((size_t)B * 4);
  int*      index_down = (int*)carve((size_t)B * CL * 4);
  int*      idx_clus   = (int*)carve((size_t)B * N * 4);
  int*      counts     = (int*)carve((size_t)B * CL * 4);
  int*      offsets    = (int*)carve((size_t)B * CL * 4);
  int*      cursor     = (int*)carve((size_t)B * CL * 4);
  int*      members    = (int*)carve((size_t)B * N * 4);
  unsigned long long* packed = (unsigned long long*)carve((size_t)B * N * 8);
  size_t used = (size_t)(w - (char*)d_ws);
  size_t per  = (size_t)N * N * 4;
  int nb_max = (ws_size > used) ? (int)((ws_size - used) / per) : 0;
  if (nb_max < 1) nb_max = 1;
  if (nb_max > B) nb_max = B;
  float* distbuf = (float*)w;

  k_init<<<(B * N) / 256, 256, 0, stream>>>(counts, distmax, packed);
  k_sq<<<B * N, 64, 0, stream>>>(x, sq);

  for (int b0 = 0; b0 < B; b0 += nb_max) {
    int nb = (B - b0 < nb_max) ? (B - b0) : nb_max;
    k_dist3<<<dim3(NTILE3, nb), 256, 0, stream>>>(x, sq, distbuf, b0);
    k_knn<<<dim3(N, nb), 256, 0, stream>>>(distbuf, density, distmax, b0);
    k_maskmin<<<dim3(N, nb), 256, 0, stream>>>(distbuf, density, distmax, score, b0);
    k_sort<<<nb, 1024, 0, stream>>>(score, index_down, b0);
    k_assign_part<<<dim3(N / 256, 8, nb), 256, 0, stream>>>(distbuf, index_down, packed, b0);
  }

  k_assign_fin<<<(B * N) / 256, 256, 0, stream>>>(packed, idx_clus);
  k_override<<<B, CL, 0, stream>>>(index_down, idx_clus);
  k_count<<<(B * N) / 256, 256, 0, stream>>>(idx_clus, counts);
  k_scan<<<1, 1024, 0, stream>>>(counts, offsets, cursor);
  k_fill<<<(B * N) / 256, 256, 0, stream>>>(idx_clus, cursor, members);
  k_gather<<<B * CL, 128, 0, stream>>>(x, members, offsets, counts, out0);
  k_final<<<(B * N) / 256, 256, 0, stream>>>(agg_weight, idx_token, idx_clus, counts, out1, out2, out3);
}

// Round 4
// 656.017 us; speedup vs baseline: 1.8372x; 1.0338x over previous
//
#include <hip/hip_runtime.h>
#include <math.h>
#include <float.h>

constexpr int B  = 4;
constexpr int N  = 3072;
constexpr int C  = 512;
constexpr int CL = 768;

// ---------------- JAX threefry2x32 (exact) ----------------
__device__ __forceinline__ unsigned rotl32(unsigned v, int d) { return (v << d) | (v >> (32 - d)); }

__device__ inline void threefry2x32(unsigned k0, unsigned k1, unsigned c0, unsigned c1,
                                    unsigned& o0, unsigned& o1) {
  unsigned ks0 = k0, ks1 = k1, ks2 = 0x1BD11BDAu ^ k0 ^ k1;
  unsigned x0 = c0 + ks0, x1 = c1 + ks1;
#define TF_RND(r) { x0 += x1; x1 = rotl32(x1, (r)); x1 ^= x0; }
  TF_RND(13) TF_RND(15) TF_RND(26) TF_RND(6)  x0 += ks1; x1 += ks2 + 1u;
  TF_RND(17) TF_RND(29) TF_RND(16) TF_RND(24) x0 += ks2; x1 += ks0 + 2u;
  TF_RND(13) TF_RND(15) TF_RND(26) TF_RND(6)  x0 += ks0; x1 += ks1 + 3u;
  TF_RND(17) TF_RND(29) TF_RND(16) TF_RND(24) x0 += ks1; x1 += ks2 + 4u;
  TF_RND(13) TF_RND(15) TF_RND(26) TF_RND(6)  x0 += ks2; x1 += ks0 + 5u;
#undef TF_RND
  o0 = x0; o1 = x1;
}

__device__ inline float jax_uniform_bn(int f) {
  constexpr int HALF = (B * N) / 2;
  unsigned o0, o1, bits;
  if (f < HALF) { threefry2x32(0u, 42u, (unsigned)f, (unsigned)(f + HALF), o0, o1); bits = o0; }
  else          { threefry2x32(0u, 42u, (unsigned)(f - HALF), (unsigned)f, o0, o1); bits = o1; }
  return __uint_as_float((bits >> 9) | 0x3f800000u) - 1.0f;
}

// ---------------- init ----------------
__global__ void k_init(int* counts, unsigned* distmax, unsigned long long* packed) {
  int g = blockIdx.x * 256 + threadIdx.x;
  packed[g] = ~0ull;
  if (g < B * CL) counts[g] = 0;
  if (g < B) distmax[g] = 0u;
}

__global__ __launch_bounds__(64) void k_sq(const float* __restrict__ x, float* __restrict__ sq) {
  int row = blockIdx.x;
  int lane = threadIdx.x;
  const float* xr = x + (size_t)row * C;
  float s = 0.f;
  for (int c = lane * 4; c < C; c += 256) {
    float4 v = *(const float4*)(xr + c);
    s += v.x * v.x + v.y * v.y + v.z * v.z + v.w * v.w;
  }
  for (int o = 32; o > 0; o >>= 1) s += __shfl_down(s, o, 64);
  if (lane == 0) sq[row] = s;
}

// ---------------- dist: 128x128 tile, 8x8 micro (split-B), BK=16, dbuf LDS ----------------
constexpr int NT3 = N / 128;                   // 24
constexpr int NTILE3 = NT3 * (NT3 + 1) / 2;    // 300

__global__ __launch_bounds__(256) void k_dist4(const float* __restrict__ x,
                                               const float* __restrict__ sq,
                                               float* __restrict__ distbuf, int b0) {
  constexpr int BK = 16;
  constexpr int STR = 132;   // 128 + 4 pad
  __shared__ float As[2][BK * STR];
  __shared__ float Bs[2][BK * STR];

  int bl = blockIdx.y, b = b0 + bl;
  int idx = blockIdx.x;
  int ti = 0, rem = idx;
  while (rem >= NT3 - ti) { rem -= NT3 - ti; ++ti; }
  int tj = ti + rem;
  int i0 = ti * 128, j0 = tj * 128;
  bool do_mirror = (ti != tj);

  const float* xb  = x + (size_t)b * N * C;
  const float* sqb = sq + (size_t)b * N;
  float* dist = distbuf + (size_t)bl * N * N;

  int tid = threadIdx.x;
  int tx = tid & 15, ty = tid >> 4;

  int srow = tid >> 2;           // 0..63
  int skq  = (tid & 3) * 4;      // 0,4,8,12
  const float* gA0 = xb + (size_t)(i0 + srow) * C + skq;
  const float* gA1 = xb + (size_t)(i0 + srow + 64) * C + skq;
  const float* gB0 = xb + (size_t)(j0 + srow) * C + skq;
  const float* gB1 = xb + (size_t)(j0 + srow + 64) * C + skq;
  int wbase = skq * STR + srow;

  float acc[8][8];
#pragma unroll
  for (int r = 0; r < 8; ++r)
#pragma unroll
    for (int c = 0; c < 8; ++c) acc[r][c] = 0.f;

  float4 pa0 = *(const float4*)gA0;
  float4 pa1 = *(const float4*)gA1;
  float4 pb0 = *(const float4*)gB0;
  float4 pb1 = *(const float4*)gB1;

  int p = 0;
  for (int k0 = 0; k0 < C; k0 += BK, p ^= 1) {
    float* wA = &As[p][wbase];
    float* wB = &Bs[p][wbase];
    wA[0] = pa0.x; wA[STR] = pa0.y; wA[2 * STR] = pa0.z; wA[3 * STR] = pa0.w;
    wA[64] = pa1.x; wA[STR + 64] = pa1.y; wA[2 * STR + 64] = pa1.z; wA[3 * STR + 64] = pa1.w;
    wB[0] = pb0.x; wB[STR] = pb0.y; wB[2 * STR] = pb0.z; wB[3 * STR] = pb0.w;
    wB[64] = pb1.x; wB[STR + 64] = pb1.y; wB[2 * STR + 64] = pb1.z; wB[3 * STR + 64] = pb1.w;
    __syncthreads();
    int kn = k0 + BK;
    if (kn < C) {
      pa0 = *(const float4*)(gA0 + kn);
      pa1 = *(const float4*)(gA1 + kn);
      pb0 = *(const float4*)(gB0 + kn);
      pb1 = *(const float4*)(gB1 + kn);
    }
    const float* Ap = As[p];
    const float* Bp = Bs[p];
#pragma unroll
    for (int kk = 0; kk < BK; ++kk) {
      float a[8], bb[8];
      const float* ar = &Ap[kk * STR + ty * 8];
      const float* br = &Bp[kk * STR + tx * 4];
      *(float4*)&a[0]  = *(const float4*)ar;
      *(float4*)&a[4]  = *(const float4*)(ar + 4);
      *(float4*)&bb[0] = *(const float4*)br;          // cols tx*4 + 0..3
      *(float4*)&bb[4] = *(const float4*)(br + 64);   // cols 64 + tx*4 + 0..3
#pragma unroll
      for (int r = 0; r < 8; ++r)
#pragma unroll
        for (int c = 0; c < 8; ++c)
          acc[r][c] = fmaf(a[r], bb[c], acc[r][c]);
    }
  }

  const float SQC = 22.627416997969522f;
  float sqi[8], sqj[8];
#pragma unroll
  for (int r = 0; r < 8; ++r) sqi[r] = sqb[i0 + ty * 8 + r];
#pragma unroll
  for (int c = 0; c < 4; ++c) {
    sqj[c]     = sqb[j0 + tx * 4 + c];
    sqj[c + 4] = sqb[j0 + 64 + tx * 4 + c];
  }
#pragma unroll
  for (int r = 0; r < 8; ++r)
#pragma unroll
    for (int c = 0; c < 8; ++c) {
      float d2 = fmaxf(sqi[r] + sqj[c] - 2.0f * acc[r][c], 0.0f);
      acc[r][c] = sqrtf(d2) / SQC;
    }

#pragma unroll
  for (int r = 0; r < 8; ++r) {
    float* drow = dist + (size_t)(i0 + ty * 8 + r) * N;
    *(float4*)(drow + j0 + tx * 4)      = make_float4(acc[r][0], acc[r][1], acc[r][2], acc[r][3]);
    *(float4*)(drow + j0 + 64 + tx * 4) = make_float4(acc[r][4], acc[r][5], acc[r][6], acc[r][7]);
  }
  if (do_mirror) {
#pragma unroll
    for (int c = 0; c < 8; ++c) {
      int jc = (c < 4) ? (j0 + tx * 4 + c) : (j0 + 64 + tx * 4 + (c - 4));
      float* dcol = dist + (size_t)jc * N + i0 + ty * 8;
      *(float4*)dcol       = make_float4(acc[0][c], acc[1][c], acc[2][c], acc[3][c]);
      *(float4*)(dcol + 4) = make_float4(acc[4][c], acc[5][c], acc[6][c], acc[7][c]);
    }
  }
}

// ---------------- 5-NN density ----------------
__device__ __forceinline__ void ins5(float* t, float v) {
  if (v < t[4]) {
    t[4] = v;
#pragma unroll
    for (int q = 4; q > 0; --q)
      if (t[q] < t[q - 1]) { float tmp = t[q]; t[q] = t[q - 1]; t[q - 1] = tmp; }
  }
}

__global__ __launch_bounds__(256) void k_knn(const float* __restrict__ distbuf,
                                             float* __restrict__ density,
                                             unsigned* __restrict__ distmax, int b0) {
  int i = blockIdx.x, bl = blockIdx.y, b = b0 + bl;
  int tid = threadIdx.x;
  const float* row = distbuf + ((size_t)bl * N + i) * N;

  float t5[5] = {FLT_MAX, FLT_MAX, FLT_MAX, FLT_MAX, FLT_MAX};
  float mx = 0.f;
  for (int j = tid * 4; j < N; j += 1024) {
    float4 v = *(const float4*)(row + j);
    mx = fmaxf(mx, fmaxf(fmaxf(v.x, v.y), fmaxf(v.z, v.w)));
    ins5(t5, v.x); ins5(t5, v.y); ins5(t5, v.z); ins5(t5, v.w);
  }
  for (int off = 32; off > 0; off >>= 1) {
    mx = fmaxf(mx, __shfl_down(mx, off, 64));
    float o0 = __shfl_down(t5[0], off, 64);
    float o1 = __shfl_down(t5[1], off, 64);
    float o2 = __shfl_down(t5[2], off, 64);
    float o3 = __shfl_down(t5[3], off, 64);
    float o4 = __shfl_down(t5[4], off, 64);
    ins5(t5, o0); ins5(t5, o1); ins5(t5, o2); ins5(t5, o3); ins5(t5, o4);
  }
  __shared__ float s5[4][5];
  __shared__ float smx[4];
  int wv = tid >> 6, ln = tid & 63;
  if (ln == 0) {
#pragma unroll
    for (int q = 0; q < 5; ++q) s5[wv][q] = t5[q];
    smx[wv] = mx;
  }
  __syncthreads();
  if (tid == 0) {
    for (int w = 1; w < 4; ++w) {
#pragma unroll
      for (int q = 0; q < 5; ++q) ins5(t5, s5[w][q]);
      mx = fmaxf(mx, smx[w]);
    }
    float sum = 0.f;
#pragma unroll
    for (int q = 0; q < 5; ++q) sum += t5[q] * t5[q];
    float dens = expf(-(sum / 5.0f)) + jax_uniform_bn(b * N + i) * 1e-6f;
    density[b * N + i] = dens;
    atomicMax(&distmax[b], __float_as_uint(mx));
  }
}

// ---------------- masked min -> score ----------------
__global__ __launch_bounds__(256) void k_maskmin(const float* __restrict__ distbuf,
                                                 const float* __restrict__ density,
                                                 const unsigned* __restrict__ distmax,
                                                 float* __restrict__ score, int b0) {
  __shared__ float sd[N];
  __shared__ float red[4];
  int i = blockIdx.x, bl = blockIdx.y, b = b0 + bl;
  int tid = threadIdx.x;
  const float* db = density + (size_t)b * N;
  for (int j = tid * 4; j < N; j += 1024) *(float4*)(sd + j) = *(const float4*)(db + j);
  __syncthreads();
  float di = sd[i];
  float dmax = __uint_as_float(distmax[b]);
  const float* row = distbuf + ((size_t)bl * N + i) * N;
  float mn = dmax;
  for (int j = tid * 4; j < N; j += 1024) {
    float4 v = *(const float4*)(row + j);
    float4 d = *(const float4*)(sd + j);
    if (d.x > di) mn = fminf(mn, v.x);
    if (d.y > di) mn = fminf(mn, v.y);
    if (d.z > di) mn = fminf(mn, v.z);
    if (d.w > di) mn = fminf(mn, v.w);
  }
  for (int off = 32; off > 0; off >>= 1) mn = fminf(mn, __shfl_down(mn, off, 64));
  if ((tid & 63) == 0) red[tid >> 6] = mn;
  __syncthreads();
  if (tid == 0) score[b * N + i] = fminf(fminf(red[0], red[1]), fminf(red[2], red[3])) * di;
}

// ---------------- top-CL sorted selection (+ inverse rank map) ----------------
__global__ __launch_bounds__(1024) void k_sort(const float* __restrict__ score,
                                               int* __restrict__ index_down,
                                               int* __restrict__ rank, int b0) {
  __shared__ float ss[4096];
  __shared__ int   si[4096];
  int b = b0 + blockIdx.x;
  int tid = threadIdx.x;
  for (int p = tid; p < 4096; p += 1024) {
    if (p < N) { ss[p] = score[b * N + p]; si[p] = p; }
    else       { ss[p] = -INFINITY; si[p] = 0x7fffffff; }
  }
  __syncthreads();
  for (int k = 2; k <= 4096; k <<= 1) {
    for (int j = k >> 1; j > 0; j >>= 1) {
      for (int p = tid; p < 4096; p += 1024) {
        int q = p ^ j;
        if (q > p) {
          float s1 = ss[p], s2 = ss[q];
          int i1 = si[p], i2 = si[q];
          bool up = ((p & k) == 0);
          bool inOrder = (s1 > s2) || (s1 == s2 && i1 < i2);
          if (inOrder != up) { ss[p] = s2; ss[q] = s1; si[p] = i2; si[q] = i1; }
        }
      }
      __syncthreads();
    }
  }
  // real scores (>=0) all sort before -inf padding, so si[0..N-1] is a permutation of 0..N-1
  for (int p = tid; p < N; p += 1024) {
    int idx = si[p];
    rank[b * N + idx] = (p < CL) ? p : -1;
    if (p < CL) index_down[b * CL + p] = idx;
  }
}

// ---------------- assignment ----------------
__global__ __launch_bounds__(256) void k_assign_part(const float* __restrict__ distbuf,
                                                     const int* __restrict__ index_down,
                                                     unsigned long long* __restrict__ packed, int b0) {
  constexpr int RCH = CL / 8;  // 96
  __shared__ int sid[RCH];
  int bl = blockIdx.z, b = b0 + bl;
  int r0 = blockIdx.y * RCH;
  int tid = threadIdx.x;
  for (int r = tid; r < RCH; r += 256) sid[r] = index_down[b * CL + r0 + r];
  __syncthreads();
  int j = blockIdx.x * 256 + tid;
  const float* base = distbuf + (size_t)bl * N * N;
  float best = FLT_MAX; int bestr = 0;
#pragma unroll 8
  for (int r = 0; r < RCH; ++r) {
    float d = base[(size_t)sid[r] * N + j];
    if (d < best) { best = d; bestr = r0 + r; }
  }
  unsigned long long key = ((unsigned long long)__float_as_uint(best) << 32) | (unsigned)bestr;
  atomicMin(&packed[b * N + j], key);
}

// fused: final assignment (centers override via rank) + histogram
__global__ void k_assign_fin2(const unsigned long long* __restrict__ packed,
                              const int* __restrict__ rank,
                              int* __restrict__ idx_cluster, int* __restrict__ counts) {
  int g = blockIdx.x * 256 + threadIdx.x;
  int b = g / N;
  int r = rank[g];
  int cl = (r >= 0) ? r : (int)(unsigned)(packed[g] & 0xffffffffull);
  idx_cluster[g] = cl;
  atomicAdd(&counts[b * CL + cl], 1);
}

// ---------------- merge ----------------
__global__ __launch_bounds__(1024) void k_scan(const int* __restrict__ counts,
                                               int* __restrict__ offsets, int* __restrict__ cursor) {
  constexpr int T = B * CL;
  __shared__ int sm[T];
  int tid = threadIdx.x;
  for (int p = tid; p < T; p += 1024) sm[p] = counts[p];
  __syncthreads();
  for (int off = 1; off < T; off <<= 1) {
    int v[3]; int n = 0;
    for (int p = tid; p < T; p += 1024) { v[n++] = (p >= off) ? sm[p - off] : 0; }
    __syncthreads();
    n = 0;
    for (int p = tid; p < T; p += 1024) { sm[p] += v[n++]; }
    __syncthreads();
  }
  for (int p = tid; p < T; p += 1024) {
    int e = sm[p] - counts[p];
    offsets[p] = e; cursor[p] = e;
  }
}

__global__ void k_fill(const int* __restrict__ idx_cluster, int* __restrict__ cursor,
                       int* __restrict__ members) {
  int g = blockIdx.x * 256 + threadIdx.x;
  int b = g / N, i = g % N;
  int seg = b * CL + idx_cluster[g];
  int pos = atomicAdd(&cursor[seg], 1);
  members[pos] = i;
}

__global__ __launch_bounds__(128) void k_gather(const float* __restrict__ x, const int* __restrict__ members,
                                                const int* __restrict__ offsets, const int* __restrict__ counts,
                                                float* __restrict__ out0) {
  int seg = blockIdx.x;
  int b = seg / CL;
  int cnt = counts[seg], off = offsets[seg];
  float nw = 1.0f / ((float)cnt + 1e-6f);
  int c = threadIdx.x * 4;
  const float* xb = x + (size_t)b * N * C;
  float4 acc = make_float4(0.f, 0.f, 0.f, 0.f);
  for (int m = 0; m < cnt; ++m) {
    int tok = members[off + m];
    float4 v = *(const float4*)(xb + (size_t)tok * C + c);
    acc.x += v.x * nw; acc.y += v.y * nw; acc.z += v.z * nw; acc.w += v.w * nw;
  }
  *(float4*)(out0 + (size_t)seg * C + c) = acc;
}

__global__ void k_final(const float* __restrict__ agg_weight, const int* __restrict__ idx_token,
                        const int* __restrict__ idx_cluster, const int* __restrict__ counts,
                        float* __restrict__ out1, float* __restrict__ out2, float* __restrict__ out3) {
  int g = blockIdx.x * 256 + threadIdx.x;
  int b = g / N;
  int it = idx_token[g];
  int clt = idx_cluster[b * N + it];
  float nwt = 1.0f / ((float)counts[b * CL + clt] + 1e-6f);
  out1[g] = agg_weight[g] * nwt;
  out2[g] = (float)clt;
  out3[g] = (float)idx_cluster[g];
}

// ---------------- launch ----------------
extern "C" void kernel_launch(void* const* d_in, const int* in_sizes, int n_in,
                              void* d_out, int out_size, void* d_ws, size_t ws_size,
                              hipStream_t stream) {
  const float* x          = (const float*)d_in[0];
  const int*   idx_token  = (const int*)d_in[1];
  const float* agg_weight = (const float*)d_in[2];

  float* out0 = (float*)d_out;
  float* out1 = out0 + (size_t)B * CL * C;
  float* out2 = out1 + (size_t)B * N;
  float* out3 = out2 + (size_t)B * N;

  char* w = (char*)d_ws;
  auto carve = [&](size_t bytes) { char* p = w; w += (bytes + 255) & ~(size_t)255; return p; };
  float*    sq         = (float*)carve((size_t)B * N * 4);
  float*    density    = (float*)carve((size_t)B * N * 4);
  float*    score      = (float*)carve((size_t)B * N * 4);
  unsigned* distmax    = (unsigned*)carve((size_t)B * 4);
  int*      index_down = (int*)carve((size_t)B * CL * 4);
  int*      rank       = (int*)carve((size_t)B * N * 4);
  int*      idx_clus   = (int*)carve((size_t)B * N * 4);
  int*      counts     = (int*)carve((size_t)B * CL * 4);
  int*      offsets    = (int*)carve((size_t)B * CL * 4);
  int*      cursor     = (int*)carve((size_t)B * CL * 4);
  int*      members    = (int*)carve((size_t)B * N * 4);
  unsigned long long* packed = (unsigned long long*)carve((size_t)B * N * 8);
  size_t used = (size_t)(w - (char*)d_ws);
  size_t per  = (size_t)N * N * 4;
  int nb_max = (ws_size > used) ? (int)((ws_size - used) / per) : 0;
  if (nb_max < 1) nb_max = 1;
  if (nb_max > B) nb_max = B;
  float* distbuf = (float*)w;

  k_init<<<(B * N) / 256, 256, 0, stream>>>(counts, distmax, packed);
  k_sq<<<B * N, 64, 0, stream>>>(x, sq);

  for (int b0 = 0; b0 < B; b0 += nb_max) {
    int nb = (B - b0 < nb_max) ? (B - b0) : nb_max;
    k_dist4<<<dim3(NTILE3, nb), 256, 0, stream>>>(x, sq, distbuf, b0);
    k_knn<<<dim3(N, nb), 256, 0, stream>>>(distbuf, density, distmax, b0);
    k_maskmin<<<dim3(N, nb), 256, 0, stream>>>(distbuf, density, distmax, score, b0);
    k_sort<<<nb, 1024, 0, stream>>>(score, index_down, rank, b0);
    k_assign_part<<<dim3(N / 256, 8, nb), 256, 0, stream>>>(distbuf, index_down, packed, b0);
  }

  k_assign_fin2<<<(B * N) / 256, 256, 0, stream>>>(packed, rank, idx_clus, counts);
  k_scan<<<1, 1024, 0, stream>>>(counts, offsets, cursor);
  k_fill<<<(B * N) / 256, 256, 0, stream>>>(idx_clus, cursor, members);
  k_gather<<<B * CL, 128, 0, stream>>>(x, members, offsets, counts, out0);
  k_final<<<(B * N) / 256, 256, 0, stream>>>(agg_weight, idx_token, idx_clus, counts, out1, out2, out3);
}

// Round 5
// 461.941 us; speedup vs baseline: 2.6090x; 1.4201x over previous
//
#include <hip/hip_runtime.h>
#include <math.h>
#include <float.h>

constexpr int B  = 4;
constexpr int N  = 3072;
constexpr int C  = 512;
constexpr int CL = 768;

typedef unsigned short u16;
typedef __attribute__((ext_vector_type(8))) short s16x8;
typedef __attribute__((ext_vector_type(4))) float f32x4;

// ---------------- JAX threefry2x32 (exact) ----------------
__device__ __forceinline__ unsigned rotl32(unsigned v, int d) { return (v << d) | (v >> (32 - d)); }

__device__ inline void threefry2x32(unsigned k0, unsigned k1, unsigned c0, unsigned c1,
                                    unsigned& o0, unsigned& o1) {
  unsigned ks0 = k0, ks1 = k1, ks2 = 0x1BD11BDAu ^ k0 ^ k1;
  unsigned x0 = c0 + ks0, x1 = c1 + ks1;
#define TF_RND(r) { x0 += x1; x1 = rotl32(x1, (r)); x1 ^= x0; }
  TF_RND(13) TF_RND(15) TF_RND(26) TF_RND(6)  x0 += ks1; x1 += ks2 + 1u;
  TF_RND(17) TF_RND(29) TF_RND(16) TF_RND(24) x0 += ks2; x1 += ks0 + 2u;
  TF_RND(13) TF_RND(15) TF_RND(26) TF_RND(6)  x0 += ks0; x1 += ks1 + 3u;
  TF_RND(17) TF_RND(29) TF_RND(16) TF_RND(24) x0 += ks1; x1 += ks2 + 4u;
  TF_RND(13) TF_RND(15) TF_RND(26) TF_RND(6)  x0 += ks2; x1 += ks0 + 5u;
#undef TF_RND
  o0 = x0; o1 = x1;
}

__device__ inline float jax_uniform_bn(int f) {
  constexpr int HALF = (B * N) / 2;
  unsigned o0, o1, bits;
  if (f < HALF) { threefry2x32(0u, 42u, (unsigned)f, (unsigned)(f + HALF), o0, o1); bits = o0; }
  else          { threefry2x32(0u, 42u, (unsigned)(f - HALF), (unsigned)f, o0, o1); bits = o1; }
  return __uint_as_float((bits >> 9) | 0x3f800000u) - 1.0f;
}

// ---------------- init ----------------
__global__ void k_init(int* counts, unsigned* distmax, unsigned long long* packed) {
  int g = blockIdx.x * 256 + threadIdx.x;
  packed[g] = ~0ull;
  if (g < B * CL) counts[g] = 0;
  if (g < B) distmax[g] = 0u;
}

__global__ __launch_bounds__(64) void k_sq(const float* __restrict__ x, float* __restrict__ sq) {
  int row = blockIdx.x;
  int lane = threadIdx.x;
  const float* xr = x + (size_t)row * C;
  float s = 0.f;
  for (int c = lane * 4; c < C; c += 256) {
    float4 v = *(const float4*)(xr + c);
    s += v.x * v.x + v.y * v.y + v.z * v.z + v.w * v.w;
  }
  for (int o = 32; o > 0; o >>= 1) s += __shfl_down(s, o, 64);
  if (lane == 0) sq[row] = s;
}

// ---------------- split x into bf16 hi/lo (3-term fp32 emulation) ----------------
__device__ __forceinline__ u16 bf16rn(float f) {
  unsigned u = __float_as_uint(f);
  unsigned r = u + 0x7FFFu + ((u >> 16) & 1u);
  return (u16)(r >> 16);
}
__device__ __forceinline__ float bf16tof(u16 h) {
  return __uint_as_float(((unsigned)h) << 16);
}

__global__ void k_split(const float* __restrict__ x, u16* __restrict__ xhi, u16* __restrict__ xlo) {
  int g = (blockIdx.x * 256 + threadIdx.x) * 4;
  float4 v = *(const float4*)(x + g);
  u16 h0 = bf16rn(v.x), h1 = bf16rn(v.y), h2 = bf16rn(v.z), h3 = bf16rn(v.w);
  u16 l0 = bf16rn(v.x - bf16tof(h0));
  u16 l1 = bf16rn(v.y - bf16tof(h1));
  u16 l2 = bf16rn(v.z - bf16tof(h2));
  u16 l3 = bf16rn(v.w - bf16tof(h3));
  uint2 hp, lp;
  hp.x = (unsigned)h0 | ((unsigned)h1 << 16); hp.y = (unsigned)h2 | ((unsigned)h3 << 16);
  lp.x = (unsigned)l0 | ((unsigned)l1 << 16); lp.y = (unsigned)l2 | ((unsigned)l3 << 16);
  *(uint2*)(xhi + g) = hp;
  *(uint2*)(xlo + g) = lp;
}

// ---------------- dist via bf16 MFMA (3-term split), 128x128 tile ----------------
constexpr int NT3 = N / 128;                   // 24
constexpr int NTILE3 = NT3 * (NT3 + 1) / 2;    // 300

__global__ __launch_bounds__(256) void k_distm(const u16* __restrict__ xhi, const u16* __restrict__ xlo,
                                               const float* __restrict__ sq,
                                               float* __restrict__ distbuf, int b0) {
  constexpr int ASTR = 40;  // u16 stride per row (80 B: 16B-aligned, mild 4-way on frags)
  __shared__ u16 sAh[128 * ASTR];
  __shared__ u16 sAl[128 * ASTR];
  __shared__ u16 sBh[128 * ASTR];
  __shared__ u16 sBl[128 * ASTR];

  int bl = blockIdx.y, b = b0 + bl;
  int idx = blockIdx.x;
  int ti = 0, rem = idx;
  while (rem >= NT3 - ti) { rem -= NT3 - ti; ++ti; }
  int tj = ti + rem;
  int i0 = ti * 128, j0 = tj * 128;
  bool do_mirror = (ti != tj);

  const float* sqb = sq + (size_t)b * N;
  float* dist = distbuf + (size_t)bl * N * N;

  int tid = threadIdx.x;
  int srow = tid >> 1, shalf = (tid & 1) * 16;     // staging: 2 threads/row, 16 bf16 each
  const u16* gAh = xhi + ((size_t)b * N + i0 + srow) * C + shalf;
  const u16* gAl = xlo + ((size_t)b * N + i0 + srow) * C + shalf;
  const u16* gBh = xhi + ((size_t)b * N + j0 + srow) * C + shalf;
  const u16* gBl = xlo + ((size_t)b * N + j0 + srow) * C + shalf;
  int wofs = srow * ASTR + shalf;

  int lane = tid & 63, w = tid >> 6;
  int wr = (w >> 1) * 64, wc = (w & 1) * 64;
  int l15 = lane & 15, l4 = lane >> 4;

  f32x4 acc[4][4];
#pragma unroll
  for (int rt = 0; rt < 4; ++rt)
#pragma unroll
    for (int ct = 0; ct < 4; ++ct)
#pragma unroll
      for (int e = 0; e < 4; ++e) acc[rt][ct][e] = 0.f;

  uint4 p0 = *(const uint4*)gAh, p1 = *(const uint4*)(gAh + 8);
  uint4 p2 = *(const uint4*)gAl, p3 = *(const uint4*)(gAl + 8);
  uint4 p4 = *(const uint4*)gBh, p5 = *(const uint4*)(gBh + 8);
  uint4 p6 = *(const uint4*)gBl, p7 = *(const uint4*)(gBl + 8);

  for (int k0 = 0; k0 < C; k0 += 32) {
    *(uint4*)&sAh[wofs] = p0; *(uint4*)&sAh[wofs + 8] = p1;
    *(uint4*)&sAl[wofs] = p2; *(uint4*)&sAl[wofs + 8] = p3;
    *(uint4*)&sBh[wofs] = p4; *(uint4*)&sBh[wofs + 8] = p5;
    *(uint4*)&sBl[wofs] = p6; *(uint4*)&sBl[wofs + 8] = p7;
    __syncthreads();
    int kn = k0 + 32;
    if (kn < C) {
      p0 = *(const uint4*)(gAh + kn); p1 = *(const uint4*)(gAh + kn + 8);
      p2 = *(const uint4*)(gAl + kn); p3 = *(const uint4*)(gAl + kn + 8);
      p4 = *(const uint4*)(gBh + kn); p5 = *(const uint4*)(gBh + kn + 8);
      p6 = *(const uint4*)(gBl + kn); p7 = *(const uint4*)(gBl + kn + 8);
    }
    s16x8 ah[4], al[4];
#pragma unroll
    for (int rt = 0; rt < 4; ++rt) {
      int ro = (wr + rt * 16 + l15) * ASTR + l4 * 8;
      ah[rt] = *(const s16x8*)&sAh[ro];
      al[rt] = *(const s16x8*)&sAl[ro];
    }
#pragma unroll
    for (int ct = 0; ct < 4; ++ct) {
      int co = (wc + ct * 16 + l15) * ASTR + l4 * 8;
      s16x8 bh = *(const s16x8*)&sBh[co];
      s16x8 bl = *(const s16x8*)&sBl[co];
#pragma unroll
      for (int rt = 0; rt < 4; ++rt) {
        acc[rt][ct] = __builtin_amdgcn_mfma_f32_16x16x32_bf16(ah[rt], bh, acc[rt][ct], 0, 0, 0);
        acc[rt][ct] = __builtin_amdgcn_mfma_f32_16x16x32_bf16(ah[rt], bl, acc[rt][ct], 0, 0, 0);
        acc[rt][ct] = __builtin_amdgcn_mfma_f32_16x16x32_bf16(al[rt], bh, acc[rt][ct], 0, 0, 0);
      }
    }
    __syncthreads();
  }

  const float SQC = 22.627416997969522f;
  // C/D layout (m89-verified): col = lane&15, row = (lane>>4)*4 + reg
  float sqi[4][4], sqj[4];
#pragma unroll
  for (int rt = 0; rt < 4; ++rt)
#pragma unroll
    for (int r = 0; r < 4; ++r) sqi[rt][r] = sqb[i0 + wr + rt * 16 + l4 * 4 + r];
#pragma unroll
  for (int ct = 0; ct < 4; ++ct) sqj[ct] = sqb[j0 + wc + ct * 16 + l15];

#pragma unroll
  for (int rt = 0; rt < 4; ++rt) {
#pragma unroll
    for (int r = 0; r < 4; ++r) {
      int row = i0 + wr + rt * 16 + l4 * 4 + r;
      float* drow = dist + (size_t)row * N;
#pragma unroll
      for (int ct = 0; ct < 4; ++ct) {
        int col = j0 + wc + ct * 16 + l15;
        float d2 = fmaxf(sqi[rt][r] + sqj[ct] - 2.0f * acc[rt][ct][r], 0.0f);
        float v = sqrtf(d2) / SQC;
        drow[col] = v;
        if (do_mirror) dist[(size_t)col * N + row] = v;
      }
    }
  }
}

// ---------------- 5-NN density ----------------
__device__ __forceinline__ void ins5(float* t, float v) {
  if (v < t[4]) {
    t[4] = v;
#pragma unroll
    for (int q = 4; q > 0; --q)
      if (t[q] < t[q - 1]) { float tmp = t[q]; t[q] = t[q - 1]; t[q - 1] = tmp; }
  }
}

__global__ __launch_bounds__(256) void k_knn(const float* __restrict__ distbuf,
                                             float* __restrict__ density,
                                             unsigned* __restrict__ distmax, int b0) {
  int i = blockIdx.x, bl = blockIdx.y, b = b0 + bl;
  int tid = threadIdx.x;
  const float* row = distbuf + ((size_t)bl * N + i) * N;

  float t5[5] = {FLT_MAX, FLT_MAX, FLT_MAX, FLT_MAX, FLT_MAX};
  float mx = 0.f;
  for (int j = tid * 4; j < N; j += 1024) {
    float4 v = *(const float4*)(row + j);
    mx = fmaxf(mx, fmaxf(fmaxf(v.x, v.y), fmaxf(v.z, v.w)));
    ins5(t5, v.x); ins5(t5, v.y); ins5(t5, v.z); ins5(t5, v.w);
  }
  for (int off = 32; off > 0; off >>= 1) {
    mx = fmaxf(mx, __shfl_down(mx, off, 64));
    float o0 = __shfl_down(t5[0], off, 64);
    float o1 = __shfl_down(t5[1], off, 64);
    float o2 = __shfl_down(t5[2], off, 64);
    float o3 = __shfl_down(t5[3], off, 64);
    float o4 = __shfl_down(t5[4], off, 64);
    ins5(t5, o0); ins5(t5, o1); ins5(t5, o2); ins5(t5, o3); ins5(t5, o4);
  }
  __shared__ float s5[4][5];
  __shared__ float smx[4];
  int wv = tid >> 6, ln = tid & 63;
  if (ln == 0) {
#pragma unroll
    for (int q = 0; q < 5; ++q) s5[wv][q] = t5[q];
    smx[wv] = mx;
  }
  __syncthreads();
  if (tid == 0) {
    for (int w = 1; w < 4; ++w) {
#pragma unroll
      for (int q = 0; q < 5; ++q) ins5(t5, s5[w][q]);
      mx = fmaxf(mx, smx[w]);
    }
    float sum = 0.f;
#pragma unroll
    for (int q = 0; q < 5; ++q) sum += t5[q] * t5[q];
    float dens = expf(-(sum / 5.0f)) + jax_uniform_bn(b * N + i) * 1e-6f;
    density[b * N + i] = dens;
    atomicMax(&distmax[b], __float_as_uint(mx));
  }
}

// ---------------- masked min -> score ----------------
__global__ __launch_bounds__(256) void k_maskmin(const float* __restrict__ distbuf,
                                                 const float* __restrict__ density,
                                                 const unsigned* __restrict__ distmax,
                                                 float* __restrict__ score, int b0) {
  __shared__ float sd[N];
  __shared__ float red[4];
  int i = blockIdx.x, bl = blockIdx.y, b = b0 + bl;
  int tid = threadIdx.x;
  const float* db = density + (size_t)b * N;
  for (int j = tid * 4; j < N; j += 1024) *(float4*)(sd + j) = *(const float4*)(db + j);
  __syncthreads();
  float di = sd[i];
  float dmax = __uint_as_float(distmax[b]);
  const float* row = distbuf + ((size_t)bl * N + i) * N;
  float mn = dmax;
  for (int j = tid * 4; j < N; j += 1024) {
    float4 v = *(const float4*)(row + j);
    float4 d = *(const float4*)(sd + j);
    if (d.x > di) mn = fminf(mn, v.x);
    if (d.y > di) mn = fminf(mn, v.y);
    if (d.z > di) mn = fminf(mn, v.z);
    if (d.w > di) mn = fminf(mn, v.w);
  }
  for (int off = 32; off > 0; off >>= 1) mn = fminf(mn, __shfl_down(mn, off, 64));
  if ((tid & 63) == 0) red[tid >> 6] = mn;
  __syncthreads();
  if (tid == 0) score[b * N + i] = fminf(fminf(red[0], red[1]), fminf(red[2], red[3])) * di;
}

// ---------------- counting-rank top-CL (replaces bitonic sort) ----------------
// rank_i = #{j: s_j > s_i or (s_j == s_i and j < i)} == stable desc-sort position
__global__ __launch_bounds__(256) void k_rank(const float* __restrict__ score,
                                              int* __restrict__ index_down,
                                              int* __restrict__ rank, int b0) {
  __shared__ float ssc[N];
  __shared__ int red[4];
  int i = blockIdx.x, b = b0 + blockIdx.y;
  int tid = threadIdx.x;
  const float* sb = score + (size_t)b * N;
  for (int j = tid * 4; j < N; j += 1024) *(float4*)(ssc + j) = *(const float4*)(sb + j);
  __syncthreads();
  float si = ssc[i];
  int cnt = 0;
  for (int j = tid * 4; j < N; j += 1024) {
    float4 v = *(const float4*)(ssc + j);
    cnt += (v.x > si) || (v.x == si && (j + 0) < i);
    cnt += (v.y > si) || (v.y == si && (j + 1) < i);
    cnt += (v.z > si) || (v.z == si && (j + 2) < i);
    cnt += (v.w > si) || (v.w == si && (j + 3) < i);
  }
  for (int off = 32; off > 0; off >>= 1) cnt += __shfl_down(cnt, off, 64);
  if ((tid & 63) == 0) red[tid >> 6] = cnt;
  __syncthreads();
  if (tid == 0) {
    int r = red[0] + red[1] + red[2] + red[3];
    rank[b * N + i] = (r < CL) ? r : -1;
    if (r < CL) index_down[b * CL + r] = i;
  }
}

// ---------------- assignment ----------------
__global__ __launch_bounds__(256) void k_assign_part(const float* __restrict__ distbuf,
                                                     const int* __restrict__ index_down,
                                                     unsigned long long* __restrict__ packed, int b0) {
  constexpr int RCH = CL / 8;  // 96
  __shared__ int sid[RCH];
  int bl = blockIdx.z, b = b0 + bl;
  int r0 = blockIdx.y * RCH;
  int tid = threadIdx.x;
  for (int r = tid; r < RCH; r += 256) sid[r] = index_down[b * CL + r0 + r];
  __syncthreads();
  int j = blockIdx.x * 256 + tid;
  const float* base = distbuf + (size_t)bl * N * N;
  float best = FLT_MAX; int bestr = 0;
#pragma unroll 8
  for (int r = 0; r < RCH; ++r) {
    float d = base[(size_t)sid[r] * N + j];
    if (d < best) { best = d; bestr = r0 + r; }
  }
  unsigned long long key = ((unsigned long long)__float_as_uint(best) << 32) | (unsigned)bestr;
  atomicMin(&packed[b * N + j], key);
}

__global__ void k_assign_fin2(const unsigned long long* __restrict__ packed,
                              const int* __restrict__ rank,
                              int* __restrict__ idx_cluster, int* __restrict__ counts) {
  int g = blockIdx.x * 256 + threadIdx.x;
  int b = g / N;
  int r = rank[g];
  int cl = (r >= 0) ? r : (int)(unsigned)(packed[g] & 0xffffffffull);
  idx_cluster[g] = cl;
  atomicAdd(&counts[b * CL + cl], 1);
}

// ---------------- merge ----------------
__global__ __launch_bounds__(1024) void k_scan(const int* __restrict__ counts,
                                               int* __restrict__ offsets, int* __restrict__ cursor) {
  constexpr int T = B * CL;
  __shared__ int sm[T];
  int tid = threadIdx.x;
  for (int p = tid; p < T; p += 1024) sm[p] = counts[p];
  __syncthreads();
  for (int off = 1; off < T; off <<= 1) {
    int v[3]; int n = 0;
    for (int p = tid; p < T; p += 1024) { v[n++] = (p >= off) ? sm[p - off] : 0; }
    __syncthreads();
    n = 0;
    for (int p = tid; p < T; p += 1024) { sm[p] += v[n++]; }
    __syncthreads();
  }
  for (int p = tid; p < T; p += 1024) {
    int e = sm[p] - counts[p];
    offsets[p] = e; cursor[p] = e;
  }
}

__global__ void k_fill(const int* __restrict__ idx_cluster, int* __restrict__ cursor,
                       int* __restrict__ members) {
  int g = blockIdx.x * 256 + threadIdx.x;
  int b = g / N, i = g % N;
  int seg = b * CL + idx_cluster[g];
  int pos = atomicAdd(&cursor[seg], 1);
  members[pos] = i;
}

__global__ __launch_bounds__(128) void k_gather(const float* __restrict__ x, const int* __restrict__ members,
                                                const int* __restrict__ offsets, const int* __restrict__ counts,
                                                float* __restrict__ out0) {
  int seg = blockIdx.x;
  int b = seg / CL;
  int cnt = counts[seg], off = offsets[seg];
  float nw = 1.0f / ((float)cnt + 1e-6f);
  int c = threadIdx.x * 4;
  const float* xb = x + (size_t)b * N * C;
  float4 acc = make_float4(0.f, 0.f, 0.f, 0.f);
  for (int m = 0; m < cnt; ++m) {
    int tok = members[off + m];
    float4 v = *(const float4*)(xb + (size_t)tok * C + c);
    acc.x += v.x * nw; acc.y += v.y * nw; acc.z += v.z * nw; acc.w += v.w * nw;
  }
  *(float4*)(out0 + (size_t)seg * C + c) = acc;
}

__global__ void k_final(const float* __restrict__ agg_weight, const int* __restrict__ idx_token,
                        const int* __restrict__ idx_cluster, const int* __restrict__ counts,
                        float* __restrict__ out1, float* __restrict__ out2, float* __restrict__ out3) {
  int g = blockIdx.x * 256 + threadIdx.x;
  int b = g / N;
  int it = idx_token[g];
  int clt = idx_cluster[b * N + it];
  float nwt = 1.0f / ((float)counts[b * CL + clt] + 1e-6f);
  out1[g] = agg_weight[g] * nwt;
  out2[g] = (float)clt;
  out3[g] = (float)idx_cluster[g];
}

// ---------------- launch ----------------
extern "C" void kernel_launch(void* const* d_in, const int* in_sizes, int n_in,
                              void* d_out, int out_size, void* d_ws, size_t ws_size,
                              hipStream_t stream) {
  const float* x          = (const float*)d_in[0];
  const int*   idx_token  = (const int*)d_in[1];
  const float* agg_weight = (const float*)d_in[2];

  float* out0 = (float*)d_out;
  float* out1 = out0 + (size_t)B * CL * C;
  float* out2 = out1 + (size_t)B * N;
  float* out3 = out2 + (size_t)B * N;

  char* w = (char*)d_ws;
  auto carve = [&](size_t bytes) { char* p = w; w += (bytes + 255) & ~(size_t)255; return p; };
  float*    sq         = (float*)carve((size_t)B * N * 4);
  float*    density    = (float*)carve((size_t)B * N * 4);
  float*    score      = (float*)carve((size_t)B * N * 4);
  unsigned* distmax    = (unsigned*)carve((size_t)B * 4);
  int*      index_down = (int*)carve((size_t)B * CL * 4);
  int*      rank       = (int*)carve((size_t)B * N * 4);
  int*      idx_clus   = (int*)carve((size_t)B * N * 4);
  int*      counts     = (int*)carve((size_t)B * CL * 4);
  int*      offsets    = (int*)carve((size_t)B * CL * 4);
  int*      cursor     = (int*)carve((size_t)B * CL * 4);
  int*      members    = (int*)carve((size_t)B * N * 4);
  unsigned long long* packed = (unsigned long long*)carve((size_t)B * N * 8);
  u16*      xhi        = (u16*)carve((size_t)B * N * C * 2);
  u16*      xlo        = (u16*)carve((size_t)B * N * C * 2);
  size_t used = (size_t)(w - (char*)d_ws);
  size_t per  = (size_t)N * N * 4;
  int nb_max = (ws_size > used) ? (int)((ws_size - used) / per) : 0;
  if (nb_max < 1) nb_max = 1;
  if (nb_max > B) nb_max = B;
  float* distbuf = (float*)w;

  k_init<<<(B * N) / 256, 256, 0, stream>>>(counts, distmax, packed);
  k_sq<<<B * N, 64, 0, stream>>>(x, sq);
  k_split<<<(B * N * C) / 1024, 256, 0, stream>>>(x, xhi, xlo);

  for (int b0 = 0; b0 < B; b0 += nb_max) {
    int nb = (B - b0 < nb_max) ? (B - b0) : nb_max;
    k_distm<<<dim3(NTILE3, nb), 256, 0, stream>>>(xhi, xlo, sq, distbuf, b0);
    k_knn<<<dim3(N, nb), 256, 0, stream>>>(distbuf, density, distmax, b0);
    k_maskmin<<<dim3(N, nb), 256, 0, stream>>>(distbuf, density, distmax, score, b0);
    k_rank<<<dim3(N, nb), 256, 0, stream>>>(score, index_down, rank, b0);
    k_assign_part<<<dim3(N / 256, 8, nb), 256, 0, stream>>>(distbuf, index_down, packed, b0);
  }

  k_assign_fin2<<<(B * N) / 256, 256, 0, stream>>>(packed, rank, idx_clus, counts);
  k_scan<<<1, 1024, 0, stream>>>(counts, offsets, cursor);
  k_fill<<<(B * N) / 256, 256, 0, stream>>>(idx_clus, cursor, members);
  k_gather<<<B * CL, 128, 0, stream>>>(x, members, offsets, counts, out0);
  k_final<<<(B * N) / 256, 256, 0, stream>>>(agg_weight, idx_token, idx_clus, counts, out1, out2, out3);
}

// Round 6
// 454.432 us; speedup vs baseline: 2.6522x; 1.0165x over previous
//
#include <hip/hip_runtime.h>
#include <math.h>
#include <float.h>

constexpr int B  = 4;
constexpr int N  = 3072;
constexpr int C  = 512;
constexpr int CL = 768;

typedef unsigned short u16;
typedef __attribute__((ext_vector_type(8))) short s16x8;
typedef __attribute__((ext_vector_type(4))) float f32x4;

// ---------------- JAX threefry2x32 (exact) ----------------
__device__ __forceinline__ unsigned rotl32(unsigned v, int d) { return (v << d) | (v >> (32 - d)); }

__device__ inline void threefry2x32(unsigned k0, unsigned k1, unsigned c0, unsigned c1,
                                    unsigned& o0, unsigned& o1) {
  unsigned ks0 = k0, ks1 = k1, ks2 = 0x1BD11BDAu ^ k0 ^ k1;
  unsigned x0 = c0 + ks0, x1 = c1 + ks1;
#define TF_RND(r) { x0 += x1; x1 = rotl32(x1, (r)); x1 ^= x0; }
  TF_RND(13) TF_RND(15) TF_RND(26) TF_RND(6)  x0 += ks1; x1 += ks2 + 1u;
  TF_RND(17) TF_RND(29) TF_RND(16) TF_RND(24) x0 += ks2; x1 += ks0 + 2u;
  TF_RND(13) TF_RND(15) TF_RND(26) TF_RND(6)  x0 += ks0; x1 += ks1 + 3u;
  TF_RND(17) TF_RND(29) TF_RND(16) TF_RND(24) x0 += ks1; x1 += ks2 + 4u;
  TF_RND(13) TF_RND(15) TF_RND(26) TF_RND(6)  x0 += ks2; x1 += ks0 + 5u;
#undef TF_RND
  o0 = x0; o1 = x1;
}

__device__ inline float jax_uniform_bn(int f) {
  constexpr int HALF = (B * N) / 2;
  unsigned o0, o1, bits;
  if (f < HALF) { threefry2x32(0u, 42u, (unsigned)f, (unsigned)(f + HALF), o0, o1); bits = o0; }
  else          { threefry2x32(0u, 42u, (unsigned)(f - HALF), (unsigned)f, o0, o1); bits = o1; }
  return __uint_as_float((bits >> 9) | 0x3f800000u) - 1.0f;
}

// ---------------- init ----------------
__global__ void k_init(int* counts, unsigned* distmax, unsigned long long* packed) {
  int g = blockIdx.x * 256 + threadIdx.x;
  packed[g] = ~0ull;
  if (g < B * CL) counts[g] = 0;
  if (g < B) distmax[g] = 0u;
}

__global__ __launch_bounds__(64) void k_sq(const float* __restrict__ x, float* __restrict__ sq) {
  int row = blockIdx.x;
  int lane = threadIdx.x;
  const float* xr = x + (size_t)row * C;
  float s = 0.f;
  for (int c = lane * 4; c < C; c += 256) {
    float4 v = *(const float4*)(xr + c);
    s += v.x * v.x + v.y * v.y + v.z * v.z + v.w * v.w;
  }
  for (int o = 32; o > 0; o >>= 1) s += __shfl_down(s, o, 64);
  if (lane == 0) sq[row] = s;
}

// ---------------- split x into bf16 hi/lo ----------------
__device__ __forceinline__ u16 bf16rn(float f) {
  unsigned u = __float_as_uint(f);
  unsigned r = u + 0x7FFFu + ((u >> 16) & 1u);
  return (u16)(r >> 16);
}
__device__ __forceinline__ float bf16tof(u16 h) {
  return __uint_as_float(((unsigned)h) << 16);
}

__global__ void k_split(const float* __restrict__ x, u16* __restrict__ xhi, u16* __restrict__ xlo) {
  int g = (blockIdx.x * 256 + threadIdx.x) * 4;
  float4 v = *(const float4*)(x + g);
  u16 h0 = bf16rn(v.x), h1 = bf16rn(v.y), h2 = bf16rn(v.z), h3 = bf16rn(v.w);
  u16 l0 = bf16rn(v.x - bf16tof(h0));
  u16 l1 = bf16rn(v.y - bf16tof(h1));
  u16 l2 = bf16rn(v.z - bf16tof(h2));
  u16 l3 = bf16rn(v.w - bf16tof(h3));
  uint2 hp, lp;
  hp.x = (unsigned)h0 | ((unsigned)h1 << 16); hp.y = (unsigned)h2 | ((unsigned)h3 << 16);
  lp.x = (unsigned)l0 | ((unsigned)l1 << 16); lp.y = (unsigned)l2 | ((unsigned)l3 << 16);
  *(uint2*)(xhi + g) = hp;
  *(uint2*)(xlo + g) = lp;
}

// ---------------- dist via bf16 MFMA (3-term split), 128x128 tile ----------------
constexpr int NT3 = N / 128;                   // 24
constexpr int NTILE3 = NT3 * (NT3 + 1) / 2;    // 300

__global__ __launch_bounds__(256) void k_distm(const u16* __restrict__ xhi, const u16* __restrict__ xlo,
                                               const float* __restrict__ sq,
                                               float* __restrict__ distbuf, int b0) {
  constexpr int ASTR = 40;
  __shared__ u16 sAh[128 * ASTR];
  __shared__ u16 sAl[128 * ASTR];
  __shared__ u16 sBh[128 * ASTR];
  __shared__ u16 sBl[128 * ASTR];

  int bl = blockIdx.y, b = b0 + bl;
  int idx = blockIdx.x;
  int ti = 0, rem = idx;
  while (rem >= NT3 - ti) { rem -= NT3 - ti; ++ti; }
  int tj = ti + rem;
  int i0 = ti * 128, j0 = tj * 128;
  bool do_mirror = (ti != tj);

  const float* sqb = sq + (size_t)b * N;
  float* dist = distbuf + (size_t)bl * N * N;

  int tid = threadIdx.x;
  int srow = tid >> 1, shalf = (tid & 1) * 16;
  const u16* gAh = xhi + ((size_t)b * N + i0 + srow) * C + shalf;
  const u16* gAl = xlo + ((size_t)b * N + i0 + srow) * C + shalf;
  const u16* gBh = xhi + ((size_t)b * N + j0 + srow) * C + shalf;
  const u16* gBl = xlo + ((size_t)b * N + j0 + srow) * C + shalf;
  int wofs = srow * ASTR + shalf;

  int lane = tid & 63, w = tid >> 6;
  int wr = (w >> 1) * 64, wc = (w & 1) * 64;
  int l15 = lane & 15, l4 = lane >> 4;

  f32x4 acc[4][4];
#pragma unroll
  for (int rt = 0; rt < 4; ++rt)
#pragma unroll
    for (int ct = 0; ct < 4; ++ct)
#pragma unroll
      for (int e = 0; e < 4; ++e) acc[rt][ct][e] = 0.f;

  uint4 p0 = *(const uint4*)gAh, p1 = *(const uint4*)(gAh + 8);
  uint4 p2 = *(const uint4*)gAl, p3 = *(const uint4*)(gAl + 8);
  uint4 p4 = *(const uint4*)gBh, p5 = *(const uint4*)(gBh + 8);
  uint4 p6 = *(const uint4*)gBl, p7 = *(const uint4*)(gBl + 8);

  for (int k0 = 0; k0 < C; k0 += 32) {
    *(uint4*)&sAh[wofs] = p0; *(uint4*)&sAh[wofs + 8] = p1;
    *(uint4*)&sAl[wofs] = p2; *(uint4*)&sAl[wofs + 8] = p3;
    *(uint4*)&sBh[wofs] = p4; *(uint4*)&sBh[wofs + 8] = p5;
    *(uint4*)&sBl[wofs] = p6; *(uint4*)&sBl[wofs + 8] = p7;
    __syncthreads();
    int kn = k0 + 32;
    if (kn < C) {
      p0 = *(const uint4*)(gAh + kn); p1 = *(const uint4*)(gAh + kn + 8);
      p2 = *(const uint4*)(gAl + kn); p3 = *(const uint4*)(gAl + kn + 8);
      p4 = *(const uint4*)(gBh + kn); p5 = *(const uint4*)(gBh + kn + 8);
      p6 = *(const uint4*)(gBl + kn); p7 = *(const uint4*)(gBl + kn + 8);
    }
    s16x8 ah[4], al[4];
#pragma unroll
    for (int rt = 0; rt < 4; ++rt) {
      int ro = (wr + rt * 16 + l15) * ASTR + l4 * 8;
      ah[rt] = *(const s16x8*)&sAh[ro];
      al[rt] = *(const s16x8*)&sAl[ro];
    }
#pragma unroll
    for (int ct = 0; ct < 4; ++ct) {
      int co = (wc + ct * 16 + l15) * ASTR + l4 * 8;
      s16x8 bh = *(const s16x8*)&sBh[co];
      s16x8 bl = *(const s16x8*)&sBl[co];
#pragma unroll
      for (int rt = 0; rt < 4; ++rt) {
        acc[rt][ct] = __builtin_amdgcn_mfma_f32_16x16x32_bf16(ah[rt], bh, acc[rt][ct], 0, 0, 0);
        acc[rt][ct] = __builtin_amdgcn_mfma_f32_16x16x32_bf16(ah[rt], bl, acc[rt][ct], 0, 0, 0);
        acc[rt][ct] = __builtin_amdgcn_mfma_f32_16x16x32_bf16(al[rt], bh, acc[rt][ct], 0, 0, 0);
      }
    }
    __syncthreads();
  }

  const float SQC = 22.627416997969522f;
  float sqi[4][4], sqj[4];
#pragma unroll
  for (int rt = 0; rt < 4; ++rt)
#pragma unroll
    for (int r = 0; r < 4; ++r) sqi[rt][r] = sqb[i0 + wr + rt * 16 + l4 * 4 + r];
#pragma unroll
  for (int ct = 0; ct < 4; ++ct) sqj[ct] = sqb[j0 + wc + ct * 16 + l15];

#pragma unroll
  for (int rt = 0; rt < 4; ++rt) {
#pragma unroll
    for (int r = 0; r < 4; ++r) {
      int row = i0 + wr + rt * 16 + l4 * 4 + r;
      float* drow = dist + (size_t)row * N;
#pragma unroll
      for (int ct = 0; ct < 4; ++ct) {
        int col = j0 + wc + ct * 16 + l15;
        float d2 = fmaxf(sqi[rt][r] + sqj[ct] - 2.0f * acc[rt][ct][r], 0.0f);
        float v = sqrtf(d2) / SQC;
        drow[col] = v;
        if (do_mirror) dist[(size_t)col * N + row] = v;
      }
    }
  }
}

// ---------------- branchless sorted-insert of v into ascending t[0..4] ----------------
__device__ __forceinline__ void ins5b(float t[5], float v) {
  float c = v;
  float n;
  n = fminf(t[0], c); c = fmaxf(t[0], c); t[0] = n;
  n = fminf(t[1], c); c = fmaxf(t[1], c); t[1] = n;
  n = fminf(t[2], c); c = fmaxf(t[2], c); t[2] = n;
  n = fminf(t[3], c); c = fmaxf(t[3], c); t[3] = n;
  t[4] = fminf(t[4], c);
}

// ---------------- 5-NN density: one wave per row ----------------
__global__ __launch_bounds__(256) void k_knn(const float* __restrict__ distbuf,
                                             float* __restrict__ density,
                                             unsigned* __restrict__ distmax, int b0) {
  int wv = threadIdx.x >> 6, lane = threadIdx.x & 63;
  int i = blockIdx.x * 4 + wv;
  int bl = blockIdx.y, b = b0 + bl;
  const float* row = distbuf + ((size_t)bl * N + i) * N;

  float t5[5] = {FLT_MAX, FLT_MAX, FLT_MAX, FLT_MAX, FLT_MAX};
  float mx = 0.f;
#pragma unroll
  for (int it = 0; it < N / 256; ++it) {
    float4 v = *(const float4*)(row + it * 256 + lane * 4);
    mx = fmaxf(mx, fmaxf(fmaxf(v.x, v.y), fmaxf(v.z, v.w)));
    ins5b(t5, v.x); ins5b(t5, v.y); ins5b(t5, v.z); ins5b(t5, v.w);
  }
#pragma unroll
  for (int m = 1; m < 64; m <<= 1) {
    mx = fmaxf(mx, __shfl_xor(mx, m, 64));
    float o0 = __shfl_xor(t5[0], m, 64);
    float o1 = __shfl_xor(t5[1], m, 64);
    float o2 = __shfl_xor(t5[2], m, 64);
    float o3 = __shfl_xor(t5[3], m, 64);
    float o4 = __shfl_xor(t5[4], m, 64);
    ins5b(t5, o0); ins5b(t5, o1); ins5b(t5, o2); ins5b(t5, o3); ins5b(t5, o4);
  }
  if (lane == 0) {
    float sum = t5[0] * t5[0] + t5[1] * t5[1] + t5[2] * t5[2] + t5[3] * t5[3] + t5[4] * t5[4];
    float dens = expf(-(sum / 5.0f)) + jax_uniform_bn(b * N + i) * 1e-6f;
    density[b * N + i] = dens;
    atomicMax(&distmax[b], __float_as_uint(mx));
  }
}

// ---------------- masked min -> score: one wave per row, shared density stage ----------------
__global__ __launch_bounds__(256) void k_maskmin(const float* __restrict__ distbuf,
                                                 const float* __restrict__ density,
                                                 const unsigned* __restrict__ distmax,
                                                 float* __restrict__ score, int b0) {
  __shared__ float sd[N];
  int tid = threadIdx.x;
  int wv = tid >> 6, lane = tid & 63;
  int i = blockIdx.x * 4 + wv;
  int bl = blockIdx.y, b = b0 + bl;
  const float* db = density + (size_t)b * N;
  for (int j = tid * 4; j < N; j += 1024) *(float4*)(sd + j) = *(const float4*)(db + j);
  __syncthreads();
  float di = sd[i];
  float dmax = __uint_as_float(distmax[b]);
  const float* row = distbuf + ((size_t)bl * N + i) * N;
  float mn = dmax;
#pragma unroll
  for (int it = 0; it < N / 256; ++it) {
    int j = it * 256 + lane * 4;
    float4 v = *(const float4*)(row + j);
    float4 d = *(const float4*)(sd + j);
    mn = fminf(mn, (d.x > di) ? v.x : dmax);
    mn = fminf(mn, (d.y > di) ? v.y : dmax);
    mn = fminf(mn, (d.z > di) ? v.z : dmax);
    mn = fminf(mn, (d.w > di) ? v.w : dmax);
  }
#pragma unroll
  for (int m = 1; m < 64; m <<= 1) mn = fminf(mn, __shfl_xor(mn, m, 64));
  if (lane == 0) score[b * N + i] = mn * di;
}

// ---------------- counting-rank top-CL: one wave per row, shared score stage ----------------
__global__ __launch_bounds__(256) void k_rank(const float* __restrict__ score,
                                              int* __restrict__ index_down,
                                              int* __restrict__ rank, int b0) {
  __shared__ float ssc[N];
  int tid = threadIdx.x;
  int wv = tid >> 6, lane = tid & 63;
  int i = blockIdx.x * 4 + wv;
  int b = b0 + blockIdx.y;
  const float* sb = score + (size_t)b * N;
  for (int j = tid * 4; j < N; j += 1024) *(float4*)(ssc + j) = *(const float4*)(sb + j);
  __syncthreads();
  float si = ssc[i];
  int cnt = 0;
#pragma unroll
  for (int it = 0; it < N / 256; ++it) {
    int j = it * 256 + lane * 4;
    float4 v = *(const float4*)(ssc + j);
    cnt += (v.x > si) || (v.x == si && (j + 0) < i);
    cnt += (v.y > si) || (v.y == si && (j + 1) < i);
    cnt += (v.z > si) || (v.z == si && (j + 2) < i);
    cnt += (v.w > si) || (v.w == si && (j + 3) < i);
  }
#pragma unroll
  for (int m = 1; m < 64; m <<= 1) cnt += __shfl_xor(cnt, m, 64);
  if (lane == 0) {
    rank[b * N + i] = (cnt < CL) ? cnt : -1;
    if (cnt < CL) index_down[b * CL + cnt] = i;
  }
}

// ---------------- assignment ----------------
__global__ __launch_bounds__(256) void k_assign_part(const float* __restrict__ distbuf,
                                                     const int* __restrict__ index_down,
                                                     unsigned long long* __restrict__ packed, int b0) {
  constexpr int RCH = CL / 8;  // 96
  __shared__ int sid[RCH];
  int bl = blockIdx.z, b = b0 + bl;
  int r0 = blockIdx.y * RCH;
  int tid = threadIdx.x;
  for (int r = tid; r < RCH; r += 256) sid[r] = index_down[b * CL + r0 + r];
  __syncthreads();
  int j = blockIdx.x * 256 + tid;
  const float* base = distbuf + (size_t)bl * N * N;
  float best = FLT_MAX; int bestr = 0;
#pragma unroll 8
  for (int r = 0; r < RCH; ++r) {
    float d = base[(size_t)sid[r] * N + j];
    if (d < best) { best = d; bestr = r0 + r; }
  }
  unsigned long long key = ((unsigned long long)__float_as_uint(best) << 32) | (unsigned)bestr;
  atomicMin(&packed[b * N + j], key);
}

__global__ void k_assign_fin2(const unsigned long long* __restrict__ packed,
                              const int* __restrict__ rank,
                              int* __restrict__ idx_cluster, int* __restrict__ counts) {
  int g = blockIdx.x * 256 + threadIdx.x;
  int b = g / N;
  int r = rank[g];
  int cl = (r >= 0) ? r : (int)(unsigned)(packed[g] & 0xffffffffull);
  idx_cluster[g] = cl;
  atomicAdd(&counts[b * CL + cl], 1);
}

// ---------------- merge ----------------
__global__ __launch_bounds__(1024) void k_scan(const int* __restrict__ counts,
                                               int* __restrict__ offsets, int* __restrict__ cursor) {
  constexpr int T = B * CL;
  __shared__ int sm[T];
  int tid = threadIdx.x;
  for (int p = tid; p < T; p += 1024) sm[p] = counts[p];
  __syncthreads();
  for (int off = 1; off < T; off <<= 1) {
    int v[3]; int n = 0;
    for (int p = tid; p < T; p += 1024) { v[n++] = (p >= off) ? sm[p - off] : 0; }
    __syncthreads();
    n = 0;
    for (int p = tid; p < T; p += 1024) { sm[p] += v[n++]; }
    __syncthreads();
  }
  for (int p = tid; p < T; p += 1024) {
    int e = sm[p] - counts[p];
    offsets[p] = e; cursor[p] = e;
  }
}

__global__ void k_fill(const int* __restrict__ idx_cluster, int* __restrict__ cursor,
                       int* __restrict__ members) {
  int g = blockIdx.x * 256 + threadIdx.x;
  int b = g / N, i = g % N;
  int seg = b * CL + idx_cluster[g];
  int pos = atomicAdd(&cursor[seg], 1);
  members[pos] = i;
}

__global__ __launch_bounds__(128) void k_gather(const float* __restrict__ x, const int* __restrict__ members,
                                                const int* __restrict__ offsets, const int* __restrict__ counts,
                                                float* __restrict__ out0) {
  int seg = blockIdx.x;
  int b = seg / CL;
  int cnt = counts[seg], off = offsets[seg];
  float nw = 1.0f / ((float)cnt + 1e-6f);
  int c = threadIdx.x * 4;
  const float* xb = x + (size_t)b * N * C;
  float4 acc = make_float4(0.f, 0.f, 0.f, 0.f);
  for (int m = 0; m < cnt; ++m) {
    int tok = members[off + m];
    float4 v = *(const float4*)(xb + (size_t)tok * C + c);
    acc.x += v.x * nw; acc.y += v.y * nw; acc.z += v.z * nw; acc.w += v.w * nw;
  }
  *(float4*)(out0 + (size_t)seg * C + c) = acc;
}

__global__ void k_final(const float* __restrict__ agg_weight, const int* __restrict__ idx_token,
                        const int* __restrict__ idx_cluster, const int* __restrict__ counts,
                        float* __restrict__ out1, float* __restrict__ out2, float* __restrict__ out3) {
  int g = blockIdx.x * 256 + threadIdx.x;
  int b = g / N;
  int it = idx_token[g];
  int clt = idx_cluster[b * N + it];
  float nwt = 1.0f / ((float)counts[b * CL + clt] + 1e-6f);
  out1[g] = agg_weight[g] * nwt;
  out2[g] = (float)clt;
  out3[g] = (float)idx_cluster[g];
}

// ---------------- launch ----------------
extern "C" void kernel_launch(void* const* d_in, const int* in_sizes, int n_in,
                              void* d_out, int out_size, void* d_ws, size_t ws_size,
                              hipStream_t stream) {
  const float* x          = (const float*)d_in[0];
  const int*   idx_token  = (const int*)d_in[1];
  const float* agg_weight = (const float*)d_in[2];

  float* out0 = (float*)d_out;
  float* out1 = out0 + (size_t)B * CL * C;
  float* out2 = out1 + (size_t)B * N;
  float* out3 = out2 + (size_t)B * N;

  char* w = (char*)d_ws;
  auto carve = [&](size_t bytes) { char* p = w; w += (bytes + 255) & ~(size_t)255; return p; };
  float*    sq         = (float*)carve((size_t)B * N * 4);
  float*    density    = (float*)carve((size_t)B * N * 4);
  float*    score      = (float*)carve((size_t)B * N * 4);
  unsigned* distmax    = (unsigned*)carve((size_t)B * 4);
  int*      index_down = (int*)carve((size_t)B * CL * 4);
  int*      rank       = (int*)carve((size_t)B * N * 4);
  int*      idx_clus   = (int*)carve((size_t)B * N * 4);
  int*      counts     = (int*)carve((size_t)B * CL * 4);
  int*      offsets    = (int*)carve((size_t)B * CL * 4);
  int*      cursor     = (int*)carve((size_t)B * CL * 4);
  int*      members    = (int*)carve((size_t)B * N * 4);
  unsigned long long* packed = (unsigned long long*)carve((size_t)B * N * 8);
  u16*      xhi        = (u16*)carve((size_t)B * N * C * 2);
  u16*      xlo        = (u16*)carve((size_t)B * N * C * 2);
  size_t used = (size_t)(w - (char*)d_ws);
  size_t per  = (size_t)N * N * 4;
  int nb_max = (ws_size > used) ? (int)((ws_size - used) / per) : 0;
  if (nb_max < 1) nb_max = 1;
  if (nb_max > B) nb_max = B;
  float* distbuf = (float*)w;

  k_init<<<(B * N) / 256, 256, 0, stream>>>(counts, distmax, packed);
  k_sq<<<B * N, 64, 0, stream>>>(x, sq);
  k_split<<<(B * N * C) / 1024, 256, 0, stream>>>(x, xhi, xlo);

  for (int b0 = 0; b0 < B; b0 += nb_max) {
    int nb = (B - b0 < nb_max) ? (B - b0) : nb_max;
    k_distm<<<dim3(NTILE3, nb), 256, 0, stream>>>(xhi, xlo, sq, distbuf, b0);
    k_knn<<<dim3(N / 4, nb), 256, 0, stream>>>(distbuf, density, distmax, b0);
    k_maskmin<<<dim3(N / 4, nb), 256, 0, stream>>>(distbuf, density, distmax, score, b0);
    k_rank<<<dim3(N / 4, nb), 256, 0, stream>>>(score, index_down, rank, b0);
    k_assign_part<<<dim3(N / 256, 8, nb), 256, 0, stream>>>(distbuf, index_down, packed, b0);
  }

  k_assign_fin2<<<(B * N) / 256, 256, 0, stream>>>(packed, rank, idx_clus, counts);
  k_scan<<<1, 1024, 0, stream>>>(counts, offsets, cursor);
  k_fill<<<(B * N) / 256, 256, 0, stream>>>(idx_clus, cursor, members);
  k_gather<<<B * CL, 128, 0, stream>>>(x, members, offsets, counts, out0);
  k_final<<<(B * N) / 256, 256, 0, stream>>>(agg_weight, idx_token, idx_clus, counts, out1, out2, out3);
}

// Round 8
// 331.704 us; speedup vs baseline: 3.6334x; 1.3700x over previous
//
#include <hip/hip_runtime.h>
#include <math.h>
#include <float.h>

constexpr int B  = 4;
constexpr int N  = 3072;
constexpr int C  = 512;
constexpr int CL = 768;

typedef unsigned short u16;
typedef __attribute__((ext_vector_type(8))) short s16x8;
typedef __attribute__((ext_vector_type(4))) float f32x4;

// ---------------- JAX threefry2x32 (exact) ----------------
__device__ __forceinline__ unsigned rotl32(unsigned v, int d) { return (v << d) | (v >> (32 - d)); }

__device__ inline void threefry2x32(unsigned k0, unsigned k1, unsigned c0, unsigned c1,
                                    unsigned& o0, unsigned& o1) {
  unsigned ks0 = k0, ks1 = k1, ks2 = 0x1BD11BDAu ^ k0 ^ k1;
  unsigned x0 = c0 + ks0, x1 = c1 + ks1;
#define TF_RND(r) { x0 += x1; x1 = rotl32(x1, (r)); x1 ^= x0; }
  TF_RND(13) TF_RND(15) TF_RND(26) TF_RND(6)  x0 += ks1; x1 += ks2 + 1u;
  TF_RND(17) TF_RND(29) TF_RND(16) TF_RND(24) x0 += ks2; x1 += ks0 + 2u;
  TF_RND(13) TF_RND(15) TF_RND(26) TF_RND(6)  x0 += ks0; x1 += ks1 + 3u;
  TF_RND(17) TF_RND(29) TF_RND(16) TF_RND(24) x0 += ks1; x1 += ks2 + 4u;
  TF_RND(13) TF_RND(15) TF_RND(26) TF_RND(6)  x0 += ks2; x1 += ks0 + 5u;
#undef TF_RND
  o0 = x0; o1 = x1;
}

__device__ inline float jax_uniform_bn(int f) {
  constexpr int HALF = (B * N) / 2;
  unsigned o0, o1, bits;
  if (f < HALF) { threefry2x32(0u, 42u, (unsigned)f, (unsigned)(f + HALF), o0, o1); bits = o0; }
  else          { threefry2x32(0u, 42u, (unsigned)(f - HALF), (unsigned)f, o0, o1); bits = o1; }
  return __uint_as_float((bits >> 9) | 0x3f800000u) - 1.0f;
}

// ---------------- init ----------------
__global__ void k_init(int* counts, unsigned long long* packed) {
  int g = blockIdx.x * 256 + threadIdx.x;
  packed[g] = ~0ull;
  if (g < B * CL) counts[g] = 0;
}

__global__ __launch_bounds__(64) void k_sq(const float* __restrict__ x, float* __restrict__ sq) {
  int row = blockIdx.x;
  int lane = threadIdx.x;
  const float* xr = x + (size_t)row * C;
  float s = 0.f;
  for (int c = lane * 4; c < C; c += 256) {
    float4 v = *(const float4*)(xr + c);
    s += v.x * v.x + v.y * v.y + v.z * v.z + v.w * v.w;
  }
  for (int o = 32; o > 0; o >>= 1) s += __shfl_down(s, o, 64);
  if (lane == 0) sq[row] = s;
}

// ---------------- split x into bf16 hi/lo ----------------
__device__ __forceinline__ u16 bf16rn(float f) {
  unsigned u = __float_as_uint(f);
  unsigned r = u + 0x7FFFu + ((u >> 16) & 1u);
  return (u16)(r >> 16);
}
__device__ __forceinline__ float bf16tof(u16 h) {
  return __uint_as_float(((unsigned)h) << 16);
}

__global__ void k_split(const float* __restrict__ x, u16* __restrict__ xhi, u16* __restrict__ xlo) {
  int g = (blockIdx.x * 256 + threadIdx.x) * 4;
  float4 v = *(const float4*)(x + g);
  u16 h0 = bf16rn(v.x), h1 = bf16rn(v.y), h2 = bf16rn(v.z), h3 = bf16rn(v.w);
  u16 l0 = bf16rn(v.x - bf16tof(h0));
  u16 l1 = bf16rn(v.y - bf16tof(h1));
  u16 l2 = bf16rn(v.z - bf16tof(h2));
  u16 l3 = bf16rn(v.w - bf16tof(h3));
  uint2 hp, lp;
  hp.x = (unsigned)h0 | ((unsigned)h1 << 16); hp.y = (unsigned)h2 | ((unsigned)h3 << 16);
  lp.x = (unsigned)l0 | ((unsigned)l1 << 16); lp.y = (unsigned)l2 | ((unsigned)l3 << 16);
  *(uint2*)(xhi + g) = hp;
  *(uint2*)(xlo + g) = lp;
}

// ---------------- dist via bf16 MFMA (3-term split), 128x128 tile ----------------
constexpr int NT3 = N / 128;                   // 24
constexpr int NTILE3 = NT3 * (NT3 + 1) / 2;    // 300

__global__ __launch_bounds__(256) void k_distm(const u16* __restrict__ xhi, const u16* __restrict__ xlo,
                                               const float* __restrict__ sq,
                                               float* __restrict__ distbuf, int b0) {
  constexpr int ASTR = 40;
  __shared__ u16 sAh[128 * ASTR];
  __shared__ u16 sAl[128 * ASTR];
  __shared__ u16 sBh[128 * ASTR];
  __shared__ u16 sBl[128 * ASTR];

  int bl = blockIdx.y, b = b0 + bl;
  int idx = blockIdx.x;
  int ti = 0, rem = idx;
  while (rem >= NT3 - ti) { rem -= NT3 - ti; ++ti; }
  int tj = ti + rem;
  int i0 = ti * 128, j0 = tj * 128;
  bool do_mirror = (ti != tj);

  const float* sqb = sq + (size_t)b * N;
  float* dist = distbuf + (size_t)bl * N * N;

  int tid = threadIdx.x;
  int srow = tid >> 1, shalf = (tid & 1) * 16;
  const u16* gAh = xhi + ((size_t)b * N + i0 + srow) * C + shalf;
  const u16* gAl = xlo + ((size_t)b * N + i0 + srow) * C + shalf;
  const u16* gBh = xhi + ((size_t)b * N + j0 + srow) * C + shalf;
  const u16* gBl = xlo + ((size_t)b * N + j0 + srow) * C + shalf;
  int wofs = srow * ASTR + shalf;

  int lane = tid & 63, w = tid >> 6;
  int wr = (w >> 1) * 64, wc = (w & 1) * 64;
  int l15 = lane & 15, l4 = lane >> 4;

  f32x4 acc[4][4];
#pragma unroll
  for (int rt = 0; rt < 4; ++rt)
#pragma unroll
    for (int ct = 0; ct < 4; ++ct)
#pragma unroll
      for (int e = 0; e < 4; ++e) acc[rt][ct][e] = 0.f;

  uint4 p0 = *(const uint4*)gAh, p1 = *(const uint4*)(gAh + 8);
  uint4 p2 = *(const uint4*)gAl, p3 = *(const uint4*)(gAl + 8);
  uint4 p4 = *(const uint4*)gBh, p5 = *(const uint4*)(gBh + 8);
  uint4 p6 = *(const uint4*)gBl, p7 = *(const uint4*)(gBl + 8);

  for (int k0 = 0; k0 < C; k0 += 32) {
    *(uint4*)&sAh[wofs] = p0; *(uint4*)&sAh[wofs + 8] = p1;
    *(uint4*)&sAl[wofs] = p2; *(uint4*)&sAl[wofs + 8] = p3;
    *(uint4*)&sBh[wofs] = p4; *(uint4*)&sBh[wofs + 8] = p5;
    *(uint4*)&sBl[wofs] = p6; *(uint4*)&sBl[wofs + 8] = p7;
    __syncthreads();
    int kn = k0 + 32;
    if (kn < C) {
      p0 = *(const uint4*)(gAh + kn); p1 = *(const uint4*)(gAh + kn + 8);
      p2 = *(const uint4*)(gAl + kn); p3 = *(const uint4*)(gAl + kn + 8);
      p4 = *(const uint4*)(gBh + kn); p5 = *(const uint4*)(gBh + kn + 8);
      p6 = *(const uint4*)(gBl + kn); p7 = *(const uint4*)(gBl + kn + 8);
    }
    s16x8 ah[4], al[4];
#pragma unroll
    for (int rt = 0; rt < 4; ++rt) {
      int ro = (wr + rt * 16 + l15) * ASTR + l4 * 8;
      ah[rt] = *(const s16x8*)&sAh[ro];
      al[rt] = *(const s16x8*)&sAl[ro];
    }
#pragma unroll
    for (int ct = 0; ct < 4; ++ct) {
      int co = (wc + ct * 16 + l15) * ASTR + l4 * 8;
      s16x8 bh = *(const s16x8*)&sBh[co];
      s16x8 bl = *(const s16x8*)&sBl[co];
#pragma unroll
      for (int rt = 0; rt < 4; ++rt) {
        acc[rt][ct] = __builtin_amdgcn_mfma_f32_16x16x32_bf16(ah[rt], bh, acc[rt][ct], 0, 0, 0);
        acc[rt][ct] = __builtin_amdgcn_mfma_f32_16x16x32_bf16(ah[rt], bl, acc[rt][ct], 0, 0, 0);
        acc[rt][ct] = __builtin_amdgcn_mfma_f32_16x16x32_bf16(al[rt], bh, acc[rt][ct], 0, 0, 0);
      }
    }
    __syncthreads();
  }

  const float SQC = 22.627416997969522f;
  float sqi[4][4], sqj[4];
#pragma unroll
  for (int rt = 0; rt < 4; ++rt)
#pragma unroll
    for (int r = 0; r < 4; ++r) sqi[rt][r] = sqb[i0 + wr + rt * 16 + l4 * 4 + r];
#pragma unroll
  for (int ct = 0; ct < 4; ++ct) sqj[ct] = sqb[j0 + wc + ct * 16 + l15];

#pragma unroll
  for (int rt = 0; rt < 4; ++rt) {
#pragma unroll
    for (int r = 0; r < 4; ++r) {
      int row = i0 + wr + rt * 16 + l4 * 4 + r;
      float* drow = dist + (size_t)row * N;
#pragma unroll
      for (int ct = 0; ct < 4; ++ct) {
        int col = j0 + wc + ct * 16 + l15;
        float d2 = fmaxf(sqi[rt][r] + sqj[ct] - 2.0f * acc[rt][ct][r], 0.0f);
        float v = sqrtf(d2) / SQC;
        drow[col] = v;
        if (do_mirror) dist[(size_t)col * N + row] = v;
      }
    }
  }
}

// ---------------- branchless sorted-insert of v into ascending t[0..4] ----------------
__device__ __forceinline__ void ins5b(float t[5], float v) {
  float c = v;
  float n;
  n = fminf(t[0], c); c = fmaxf(t[0], c); t[0] = n;
  n = fminf(t[1], c); c = fmaxf(t[1], c); t[1] = n;
  n = fminf(t[2], c); c = fmaxf(t[2], c); t[2] = n;
  n = fminf(t[3], c); c = fmaxf(t[3], c); t[3] = n;
  t[4] = fminf(t[4], c);
}

// ---------------- 5-NN density: one wave per row; rowmax via plain store ----------------
__global__ __launch_bounds__(256) void k_knn(const float* __restrict__ distbuf,
                                             float* __restrict__ density,
                                             float* __restrict__ rowmax, int b0) {
  int wv = threadIdx.x >> 6, lane = threadIdx.x & 63;
  int i = blockIdx.x * 4 + wv;
  int bl = blockIdx.y, b = b0 + bl;
  const float* row = distbuf + ((size_t)bl * N + i) * N;

  float t5[5] = {FLT_MAX, FLT_MAX, FLT_MAX, FLT_MAX, FLT_MAX};
  float mx = 0.f;
#pragma unroll
  for (int it = 0; it < N / 256; ++it) {
    float4 v = *(const float4*)(row + it * 256 + lane * 4);
    mx = fmaxf(mx, fmaxf(fmaxf(v.x, v.y), fmaxf(v.z, v.w)));
    ins5b(t5, v.x); ins5b(t5, v.y); ins5b(t5, v.z); ins5b(t5, v.w);
  }
#pragma unroll
  for (int m = 1; m < 64; m <<= 1) {
    mx = fmaxf(mx, __shfl_xor(mx, m, 64));
    float o0 = __shfl_xor(t5[0], m, 64);
    float o1 = __shfl_xor(t5[1], m, 64);
    float o2 = __shfl_xor(t5[2], m, 64);
    float o3 = __shfl_xor(t5[3], m, 64);
    float o4 = __shfl_xor(t5[4], m, 64);
    ins5b(t5, o0); ins5b(t5, o1); ins5b(t5, o2); ins5b(t5, o3); ins5b(t5, o4);
  }
  if (lane == 0) {
    float sum = t5[0] * t5[0] + t5[1] * t5[1] + t5[2] * t5[2] + t5[3] * t5[3] + t5[4] * t5[4];
    float dens = expf(-(sum / 5.0f)) + jax_uniform_bn(b * N + i) * 1e-6f;
    density[b * N + i] = dens;
    rowmax[b * N + i] = mx;   // no atomic: plain store, reduced by k_dmax
  }
}

// ---------------- distmax[b] = max over rowmax[b,:] (replaces same-address atomicMax) ----------------
__global__ __launch_bounds__(1024) void k_dmax(const float* __restrict__ rowmax,
                                               float* __restrict__ distmax) {
  __shared__ float red[16];
  int b = blockIdx.x;
  int tid = threadIdx.x;
  const float* rb = rowmax + (size_t)b * N;
  float mx = 0.f;
  for (int j = tid; j < N; j += 1024) mx = fmaxf(mx, rb[j]);
#pragma unroll
  for (int m = 1; m < 64; m <<= 1) mx = fmaxf(mx, __shfl_xor(mx, m, 64));
  if ((tid & 63) == 0) red[tid >> 6] = mx;
  __syncthreads();
  if (tid == 0) {
    float r = red[0];
#pragma unroll
    for (int q = 1; q < 16; ++q) r = fmaxf(r, red[q]);
    distmax[b] = r;
  }
}

// ---------------- masked min -> score: one wave per row, shared density stage ----------------
__global__ __launch_bounds__(256) void k_maskmin(const float* __restrict__ distbuf,
                                                 const float* __restrict__ density,
                                                 const float* __restrict__ distmax,
                                                 float* __restrict__ score, int b0) {
  __shared__ float sd[N];
  int tid = threadIdx.x;
  int wv = tid >> 6, lane = tid & 63;
  int i = blockIdx.x * 4 + wv;
  int bl = blockIdx.y, b = b0 + bl;
  const float* db = density + (size_t)b * N;
  for (int j = tid * 4; j < N; j += 1024) *(float4*)(sd + j) = *(const float4*)(db + j);
  __syncthreads();
  float di = sd[i];
  float dmax = distmax[b];
  const float* row = distbuf + ((size_t)bl * N + i) * N;
  float mn = dmax;
#pragma unroll
  for (int it = 0; it < N / 256; ++it) {
    int j = it * 256 + lane * 4;
    float4 v = *(const float4*)(row + j);
    float4 d = *(const float4*)(sd + j);
    mn = fminf(mn, (d.x > di) ? v.x : dmax);
    mn = fminf(mn, (d.y > di) ? v.y : dmax);
    mn = fminf(mn, (d.z > di) ? v.z : dmax);
    mn = fminf(mn, (d.w > di) ? v.w : dmax);
  }
#pragma unroll
  for (int m = 1; m < 64; m <<= 1) mn = fminf(mn, __shfl_xor(mn, m, 64));
  if (lane == 0) score[b * N + i] = mn * di;
}

// ---------------- counting-rank top-CL: one wave per row, shared score stage ----------------
__global__ __launch_bounds__(256) void k_rank(const float* __restrict__ score,
                                              int* __restrict__ index_down,
                                              int* __restrict__ rank, int b0) {
  __shared__ float ssc[N];
  int tid = threadIdx.x;
  int wv = tid >> 6, lane = tid & 63;
  int i = blockIdx.x * 4 + wv;
  int b = b0 + blockIdx.y;
  const float* sb = score + (size_t)b * N;
  for (int j = tid * 4; j < N; j += 1024) *(float4*)(ssc + j) = *(const float4*)(sb + j);
  __syncthreads();
  float si = ssc[i];
  int cnt = 0;
#pragma unroll
  for (int it = 0; it < N / 256; ++it) {
    int j = it * 256 + lane * 4;
    float4 v = *(const float4*)(ssc + j);
    cnt += (v.x > si) || (v.x == si && (j + 0) < i);
    cnt += (v.y > si) || (v.y == si && (j + 1) < i);
    cnt += (v.z > si) || (v.z == si && (j + 2) < i);
    cnt += (v.w > si) || (v.w == si && (j + 3) < i);
  }
#pragma unroll
  for (int m = 1; m < 64; m <<= 1) cnt += __shfl_xor(cnt, m, 64);
  if (lane == 0) {
    rank[b * N + i] = (cnt < CL) ? cnt : -1;
    if (cnt < CL) index_down[b * CL + cnt] = i;
  }
}

// ---------------- assignment ----------------
__global__ __launch_bounds__(256) void k_assign_part(const float* __restrict__ distbuf,
                                                     const int* __restrict__ index_down,
                                                     unsigned long long* __restrict__ packed, int b0) {
  constexpr int RCH = CL / 8;  // 96
  __shared__ int sid[RCH];
  int bl = blockIdx.z, b = b0 + bl;
  int r0 = blockIdx.y * RCH;
  int tid = threadIdx.x;
  for (int r = tid; r < RCH; r += 256) sid[r] = index_down[b * CL + r0 + r];
  __syncthreads();
  int j = blockIdx.x * 256 + tid;
  const float* base = distbuf + (size_t)bl * N * N;
  float best = FLT_MAX; int bestr = 0;
#pragma unroll 8
  for (int r = 0; r < RCH; ++r) {
    float d = base[(size_t)sid[r] * N + j];
    if (d < best) { best = d; bestr = r0 + r; }
  }
  unsigned long long key = ((unsigned long long)__float_as_uint(best) << 32) | (unsigned)bestr;
  atomicMin(&packed[b * N + j], key);
}

__global__ void k_assign_fin2(const unsigned long long* __restrict__ packed,
                              const int* __restrict__ rank,
                              int* __restrict__ idx_cluster, int* __restrict__ counts) {
  int g = blockIdx.x * 256 + threadIdx.x;
  int b = g / N;
  int r = rank[g];
  int cl = (r >= 0) ? r : (int)(unsigned)(packed[g] & 0xffffffffull);
  idx_cluster[g] = cl;
  atomicAdd(&counts[b * CL + cl], 1);
}

// ---------------- merge ----------------
__global__ __launch_bounds__(1024) void k_scan(const int* __restrict__ counts,
                                               int* __restrict__ offsets, int* __restrict__ cursor) {
  constexpr int T = B * CL;
  __shared__ int sm[T];
  int tid = threadIdx.x;
  for (int p = tid; p < T; p += 1024) sm[p] = counts[p];
  __syncthreads();
  for (int off = 1; off < T; off <<= 1) {
    int v[3]; int n = 0;
    for (int p = tid; p < T; p += 1024) { v[n++] = (p >= off) ? sm[p - off] : 0; }
    __syncthreads();
    n = 0;
    for (int p = tid; p < T; p += 1024) { sm[p] += v[n++]; }
    __syncthreads();
  }
  for (int p = tid; p < T; p += 1024) {
    int e = sm[p] - counts[p];
    offsets[p] = e; cursor[p] = e;
  }
}

__global__ void k_fill(const int* __restrict__ idx_cluster, int* __restrict__ cursor,
                       int* __restrict__ members) {
  int g = blockIdx.x * 256 + threadIdx.x;
  int b = g / N, i = g % N;
  int seg = b * CL + idx_cluster[g];
  int pos = atomicAdd(&cursor[seg], 1);
  members[pos] = i;
}

__global__ __launch_bounds__(128) void k_gather(const float* __restrict__ x, const int* __restrict__ members,
                                                const int* __restrict__ offsets, const int* __restrict__ counts,
                                                float* __restrict__ out0) {
  int seg = blockIdx.x;
  int b = seg / CL;
  int cnt = counts[seg], off = offsets[seg];
  float nw = 1.0f / ((float)cnt + 1e-6f);
  int c = threadIdx.x * 4;
  const float* xb = x + (size_t)b * N * C;
  float4 acc = make_float4(0.f, 0.f, 0.f, 0.f);
  for (int m = 0; m < cnt; ++m) {
    int tok = members[off + m];
    float4 v = *(const float4*)(xb + (size_t)tok * C + c);
    acc.x += v.x * nw; acc.y += v.y * nw; acc.z += v.z * nw; acc.w += v.w * nw;
  }
  *(float4*)(out0 + (size_t)seg * C + c) = acc;
}

__global__ void k_final(const float* __restrict__ agg_weight, const int* __restrict__ idx_token,
                        const int* __restrict__ idx_cluster, const int* __restrict__ counts,
                        float* __restrict__ out1, float* __restrict__ out2, float* __restrict__ out3) {
  int g = blockIdx.x * 256 + threadIdx.x;
  int b = g / N;
  int it = idx_token[g];
  int clt = idx_cluster[b * N + it];
  float nwt = 1.0f / ((float)counts[b * CL + clt] + 1e-6f);
  out1[g] = agg_weight[g] * nwt;
  out2[g] = (float)clt;
  out3[g] = (float)idx_cluster[g];
}

// ---------------- launch ----------------
extern "C" void kernel_launch(void* const* d_in, const int* in_sizes, int n_in,
                              void* d_out, int out_size, void* d_ws, size_t ws_size,
                              hipStream_t stream) {
  const float* x          = (const float*)d_in[0];
  const int*   idx_token  = (const int*)d_in[1];
  const float* agg_weight = (const float*)d_in[2];

  float* out0 = (float*)d_out;
  float* out1 = out0 + (size_t)B * CL * C;
  float* out2 = out1 + (size_t)B * N;
  float* out3 = out2 + (size_t)B * N;

  char* w = (char*)d_ws;
  auto carve = [&](size_t bytes) { char* p = w; w += (bytes + 255) & ~(size_t)255; return p; };
  float*    sq         = (float*)carve((size_t)B * N * 4);
  float*    density    = (float*)carve((size_t)B * N * 4);
  float*    score      = (float*)carve((size_t)B * N * 4);
  float*    rowmax     = (float*)carve((size_t)B * N * 4);
  float*    distmax    = (float*)carve((size_t)B * 4);
  int*      index_down = (int*)carve((size_t)B * CL * 4);
  int*      rank       = (int*)carve((size_t)B * N * 4);
  int*      idx_clus   = (int*)carve((size_t)B * N * 4);
  int*      counts     = (int*)carve((size_t)B * CL * 4);
  int*      offsets    = (int*)carve((size_t)B * CL * 4);
  int*      cursor     = (int*)carve((size_t)B * CL * 4);
  int*      members    = (int*)carve((size_t)B * N * 4);
  unsigned long long* packed = (unsigned long long*)carve((size_t)B * N * 8);
  u16*      xhi        = (u16*)carve((size_t)B * N * C * 2);
  u16*      xlo        = (u16*)carve((size_t)B * N * C * 2);
  size_t used = (size_t)(w - (char*)d_ws);
  size_t per  = (size_t)N * N * 4;
  int nb_max = (ws_size > used) ? (int)((ws_size - used) / per) : 0;
  if (nb_max < 1) nb_max = 1;
  if (nb_max > B) nb_max = B;
  float* distbuf = (float*)w;

  k_init<<<(B * N) / 256, 256, 0, stream>>>(counts, packed);
  k_sq<<<B * N, 64, 0, stream>>>(x, sq);
  k_split<<<(B * N * C) / 1024, 256, 0, stream>>>(x, xhi, xlo);

  for (int b0 = 0; b0 < B; b0 += nb_max) {
    int nb = (B - b0 < nb_max) ? (B - b0) : nb_max;
    k_distm<<<dim3(NTILE3, nb), 256, 0, stream>>>(xhi, xlo, sq, distbuf, b0);
    k_knn<<<dim3(N / 4, nb), 256, 0, stream>>>(distbuf, density, rowmax, b0);
    k_dmax<<<nb, 1024, 0, stream>>>(rowmax + (size_t)b0 * N, distmax + b0);
    k_maskmin<<<dim3(N / 4, nb), 256, 0, stream>>>(distbuf, density, distmax, score, b0);
    k_rank<<<dim3(N / 4, nb), 256, 0, stream>>>(score, index_down, rank, b0);
    k_assign_part<<<dim3(N / 256, 8, nb), 256, 0, stream>>>(distbuf, index_down, packed, b0);
  }

  k_assign_fin2<<<(B * N) / 256, 256, 0, stream>>>(packed, rank, idx_clus, counts);
  k_scan<<<1, 1024, 0, stream>>>(counts, offsets, cursor);
  k_fill<<<(B * N) / 256, 256, 0, stream>>>(idx_clus, cursor, members);
  k_gather<<<B * CL, 128, 0, stream>>>(x, members, offsets, counts, out0);
  k_final<<<(B * N) / 256, 256, 0, stream>>>(agg_weight, idx_token, idx_clus, counts, out1, out2, out3);
}

// Round 9
// 308.620 us; speedup vs baseline: 3.9052x; 1.0748x over previous
//
#include <hip/hip_runtime.h>
#include <math.h>
#include <float.h>

constexpr int B  = 4;
constexpr int N  = 3072;
constexpr int C  = 512;
constexpr int CL = 768;

typedef unsigned short u16;
typedef __attribute__((ext_vector_type(8))) short s16x8;
typedef __attribute__((ext_vector_type(4))) float f32x4;

// ---------------- JAX threefry2x32 (exact) ----------------
__device__ __forceinline__ unsigned rotl32(unsigned v, int d) { return (v << d) | (v >> (32 - d)); }

__device__ inline void threefry2x32(unsigned k0, unsigned k1, unsigned c0, unsigned c1,
                                    unsigned& o0, unsigned& o1) {
  unsigned ks0 = k0, ks1 = k1, ks2 = 0x1BD11BDAu ^ k0 ^ k1;
  unsigned x0 = c0 + ks0, x1 = c1 + ks1;
#define TF_RND(r) { x0 += x1; x1 = rotl32(x1, (r)); x1 ^= x0; }
  TF_RND(13) TF_RND(15) TF_RND(26) TF_RND(6)  x0 += ks1; x1 += ks2 + 1u;
  TF_RND(17) TF_RND(29) TF_RND(16) TF_RND(24) x0 += ks2; x1 += ks0 + 2u;
  TF_RND(13) TF_RND(15) TF_RND(26) TF_RND(6)  x0 += ks0; x1 += ks1 + 3u;
  TF_RND(17) TF_RND(29) TF_RND(16) TF_RND(24) x0 += ks1; x1 += ks2 + 4u;
  TF_RND(13) TF_RND(15) TF_RND(26) TF_RND(6)  x0 += ks2; x1 += ks0 + 5u;
#undef TF_RND
  o0 = x0; o1 = x1;
}

__device__ inline float jax_uniform_bn(int f) {
  constexpr int HALF = (B * N) / 2;
  unsigned o0, o1, bits;
  if (f < HALF) { threefry2x32(0u, 42u, (unsigned)f, (unsigned)(f + HALF), o0, o1); bits = o0; }
  else          { threefry2x32(0u, 42u, (unsigned)(f - HALF), (unsigned)f, o0, o1); bits = o1; }
  return __uint_as_float((bits >> 9) | 0x3f800000u) - 1.0f;
}

// ---------------- init ----------------
__global__ void k_init(int* counts, unsigned long long* packed) {
  int g = blockIdx.x * 256 + threadIdx.x;
  packed[g] = ~0ull;
  if (g < B * CL) counts[g] = 0;
}

__global__ __launch_bounds__(64) void k_sq(const float* __restrict__ x, float* __restrict__ sq) {
  int row = blockIdx.x;
  int lane = threadIdx.x;
  const float* xr = x + (size_t)row * C;
  float s = 0.f;
  for (int c = lane * 4; c < C; c += 256) {
    float4 v = *(const float4*)(xr + c);
    s += v.x * v.x + v.y * v.y + v.z * v.z + v.w * v.w;
  }
  for (int o = 32; o > 0; o >>= 1) s += __shfl_down(s, o, 64);
  if (lane == 0) sq[row] = s;
}

// ---------------- split x into bf16 hi/lo ----------------
__device__ __forceinline__ u16 bf16rn(float f) {
  unsigned u = __float_as_uint(f);
  unsigned r = u + 0x7FFFu + ((u >> 16) & 1u);
  return (u16)(r >> 16);
}
__device__ __forceinline__ float bf16tof(u16 h) {
  return __uint_as_float(((unsigned)h) << 16);
}

__global__ void k_split(const float* __restrict__ x, u16* __restrict__ xhi, u16* __restrict__ xlo) {
  int g = (blockIdx.x * 256 + threadIdx.x) * 4;
  float4 v = *(const float4*)(x + g);
  u16 h0 = bf16rn(v.x), h1 = bf16rn(v.y), h2 = bf16rn(v.z), h3 = bf16rn(v.w);
  u16 l0 = bf16rn(v.x - bf16tof(h0));
  u16 l1 = bf16rn(v.y - bf16tof(h1));
  u16 l2 = bf16rn(v.z - bf16tof(h2));
  u16 l3 = bf16rn(v.w - bf16tof(h3));
  uint2 hp, lp;
  hp.x = (unsigned)h0 | ((unsigned)h1 << 16); hp.y = (unsigned)h2 | ((unsigned)h3 << 16);
  lp.x = (unsigned)l0 | ((unsigned)l1 << 16); lp.y = (unsigned)l2 | ((unsigned)l3 << 16);
  *(uint2*)(xhi + g) = hp;
  *(uint2*)(xlo + g) = lp;
}

// ---------------- dist via bf16 MFMA (3-term split), 128x128 tile ----------------
constexpr int NT3 = N / 128;                   // 24
constexpr int NTILE3 = NT3 * (NT3 + 1) / 2;    // 300

__global__ __launch_bounds__(256) void k_distm(const u16* __restrict__ xhi, const u16* __restrict__ xlo,
                                               const float* __restrict__ sq,
                                               float* __restrict__ distbuf, int b0) {
  constexpr int ASTR = 40;
  // 40960 B shared: K-loop staging (4 x 128*40 u16), reused as epilogue
  // transpose buffer (4 waves x 32 cols x 76-float stride = 38912 B).
  __shared__ __align__(16) char smem[40960];
  u16* sAh = (u16*)smem;
  u16* sAl = sAh + 128 * ASTR;
  u16* sBh = sAl + 128 * ASTR;
  u16* sBl = sBh + 128 * ASTR;

  int bl = blockIdx.y, b = b0 + bl;
  int idx = blockIdx.x;
  int ti = 0, rem = idx;
  while (rem >= NT3 - ti) { rem -= NT3 - ti; ++ti; }
  int tj = ti + rem;
  int i0 = ti * 128, j0 = tj * 128;
  bool do_mirror = (ti != tj);

  const float* sqb = sq + (size_t)b * N;
  float* dist = distbuf + (size_t)bl * N * N;

  int tid = threadIdx.x;
  int srow = tid >> 1, shalf = (tid & 1) * 16;
  const u16* gAh = xhi + ((size_t)b * N + i0 + srow) * C + shalf;
  const u16* gAl = xlo + ((size_t)b * N + i0 + srow) * C + shalf;
  const u16* gBh = xhi + ((size_t)b * N + j0 + srow) * C + shalf;
  const u16* gBl = xlo + ((size_t)b * N + j0 + srow) * C + shalf;
  int wofs = srow * ASTR + shalf;

  int lane = tid & 63, w = tid >> 6;
  int wr = (w >> 1) * 64, wc = (w & 1) * 64;
  int l15 = lane & 15, l4 = lane >> 4;

  f32x4 acc[4][4];
#pragma unroll
  for (int rt = 0; rt < 4; ++rt)
#pragma unroll
    for (int ct = 0; ct < 4; ++ct)
#pragma unroll
      for (int e = 0; e < 4; ++e) acc[rt][ct][e] = 0.f;

  uint4 p0 = *(const uint4*)gAh, p1 = *(const uint4*)(gAh + 8);
  uint4 p2 = *(const uint4*)gAl, p3 = *(const uint4*)(gAl + 8);
  uint4 p4 = *(const uint4*)gBh, p5 = *(const uint4*)(gBh + 8);
  uint4 p6 = *(const uint4*)gBl, p7 = *(const uint4*)(gBl + 8);

  for (int k0 = 0; k0 < C; k0 += 32) {
    *(uint4*)&sAh[wofs] = p0; *(uint4*)&sAh[wofs + 8] = p1;
    *(uint4*)&sAl[wofs] = p2; *(uint4*)&sAl[wofs + 8] = p3;
    *(uint4*)&sBh[wofs] = p4; *(uint4*)&sBh[wofs + 8] = p5;
    *(uint4*)&sBl[wofs] = p6; *(uint4*)&sBl[wofs + 8] = p7;
    __syncthreads();
    int kn = k0 + 32;
    if (kn < C) {
      p0 = *(const uint4*)(gAh + kn); p1 = *(const uint4*)(gAh + kn + 8);
      p2 = *(const uint4*)(gAl + kn); p3 = *(const uint4*)(gAl + kn + 8);
      p4 = *(const uint4*)(gBh + kn); p5 = *(const uint4*)(gBh + kn + 8);
      p6 = *(const uint4*)(gBl + kn); p7 = *(const uint4*)(gBl + kn + 8);
    }
    s16x8 ah[4], al[4];
#pragma unroll
    for (int rt = 0; rt < 4; ++rt) {
      int ro = (wr + rt * 16 + l15) * ASTR + l4 * 8;
      ah[rt] = *(const s16x8*)&sAh[ro];
      al[rt] = *(const s16x8*)&sAl[ro];
    }
#pragma unroll
    for (int ct = 0; ct < 4; ++ct) {
      int co = (wc + ct * 16 + l15) * ASTR + l4 * 8;
      s16x8 bh = *(const s16x8*)&sBh[co];
      s16x8 bl = *(const s16x8*)&sBl[co];
#pragma unroll
      for (int rt = 0; rt < 4; ++rt) {
        acc[rt][ct] = __builtin_amdgcn_mfma_f32_16x16x32_bf16(ah[rt], bh, acc[rt][ct], 0, 0, 0);
        acc[rt][ct] = __builtin_amdgcn_mfma_f32_16x16x32_bf16(ah[rt], bl, acc[rt][ct], 0, 0, 0);
        acc[rt][ct] = __builtin_amdgcn_mfma_f32_16x16x32_bf16(al[rt], bh, acc[rt][ct], 0, 0, 0);
      }
    }
    __syncthreads();   // also guards smem reuse by the epilogue below
  }

  const float SQC = 22.627416997969522f;
  float sqi[4][4], sqj[4];
#pragma unroll
  for (int rt = 0; rt < 4; ++rt)
#pragma unroll
    for (int r = 0; r < 4; ++r) sqi[rt][r] = sqb[i0 + wr + rt * 16 + l4 * 4 + r];
#pragma unroll
  for (int ct = 0; ct < 4; ++ct) sqj[ct] = sqb[j0 + wc + ct * 16 + l15];

#pragma unroll
  for (int rt = 0; rt < 4; ++rt)
#pragma unroll
    for (int ct = 0; ct < 4; ++ct)
#pragma unroll
      for (int r = 0; r < 4; ++r) {
        float d2 = fmaxf(sqi[rt][r] + sqj[ct] - 2.0f * acc[rt][ct][r], 0.0f);
        acc[rt][ct][r] = sqrtf(d2) / SQC;
      }

  // ---- epilogue: per-wave LDS transpose (32-col passes), coalesced float4 writes.
  // Each wave uses its private region; within-wave LDS ordering needs no barrier.
  constexpr int TSTR = 76;  // float stride per col; 16B-aligned readbacks
  float* sT = (float*)smem + w * (32 * TSTR);

#pragma unroll
  for (int p = 0; p < 2; ++p) {
    // stage: cols ct=2p,2p+1 -> sT[cl][rl]  (cl=0..31, rl=0..63)
#pragma unroll
    for (int cth = 0; cth < 2; ++cth) {
      int ct = p * 2 + cth;
      int cl = cth * 16 + l15;
#pragma unroll
      for (int rt = 0; rt < 4; ++rt)
#pragma unroll
        for (int r = 0; r < 4; ++r)
          sT[cl * TSTR + rt * 16 + l4 * 4 + r] = acc[rt][ct][r];
    }
    // direct write: rows i0+wr+rl, cols j0+wc+p*32 + 4g..4g+3
    {
      int g4 = lane & 7, rbase = lane >> 3;
#pragma unroll
      for (int it = 0; it < 8; ++it) {
        int rl = it * 8 + rbase;
        float4 v = make_float4(sT[(4 * g4 + 0) * TSTR + rl],
                               sT[(4 * g4 + 1) * TSTR + rl],
                               sT[(4 * g4 + 2) * TSTR + rl],
                               sT[(4 * g4 + 3) * TSTR + rl]);
        *(float4*)(dist + (size_t)(i0 + wr + rl) * N + j0 + wc + p * 32 + 4 * g4) = v;
      }
    }
    // mirror write: rows j0+wc+p*32+c, cols i0+wr + rq*4
    if (do_mirror) {
      int cg = lane >> 4, rq = lane & 15;
#pragma unroll
      for (int cc = 0; cc < 8; ++cc) {
        int c = cc * 4 + cg;
        float4 v = *(const float4*)&sT[c * TSTR + rq * 4];
        *(float4*)(dist + (size_t)(j0 + wc + p * 32 + c) * N + i0 + wr + rq * 4) = v;
      }
    }
  }
}

// ---------------- branchless sorted-insert of v into ascending t[0..4] ----------------
__device__ __forceinline__ void ins5b(float t[5], float v) {
  float c = v;
  float n;
  n = fminf(t[0], c); c = fmaxf(t[0], c); t[0] = n;
  n = fminf(t[1], c); c = fmaxf(t[1], c); t[1] = n;
  n = fminf(t[2], c); c = fmaxf(t[2], c); t[2] = n;
  n = fminf(t[3], c); c = fmaxf(t[3], c); t[3] = n;
  t[4] = fminf(t[4], c);
}

// ---------------- 5-NN density: one wave per row; rowmax via plain store ----------------
__global__ __launch_bounds__(256) void k_knn(const float* __restrict__ distbuf,
                                             float* __restrict__ density,
                                             float* __restrict__ rowmax, int b0) {
  int wv = threadIdx.x >> 6, lane = threadIdx.x & 63;
  int i = blockIdx.x * 4 + wv;
  int bl = blockIdx.y, b = b0 + bl;
  const float* row = distbuf + ((size_t)bl * N + i) * N;

  float t5[5] = {FLT_MAX, FLT_MAX, FLT_MAX, FLT_MAX, FLT_MAX};
  float mx = 0.f;
#pragma unroll
  for (int it = 0; it < N / 256; ++it) {
    float4 v = *(const float4*)(row + it * 256 + lane * 4);
    mx = fmaxf(mx, fmaxf(fmaxf(v.x, v.y), fmaxf(v.z, v.w)));
    ins5b(t5, v.x); ins5b(t5, v.y); ins5b(t5, v.z); ins5b(t5, v.w);
  }
#pragma unroll
  for (int m = 1; m < 64; m <<= 1) {
    mx = fmaxf(mx, __shfl_xor(mx, m, 64));
    float o0 = __shfl_xor(t5[0], m, 64);
    float o1 = __shfl_xor(t5[1], m, 64);
    float o2 = __shfl_xor(t5[2], m, 64);
    float o3 = __shfl_xor(t5[3], m, 64);
    float o4 = __shfl_xor(t5[4], m, 64);
    ins5b(t5, o0); ins5b(t5, o1); ins5b(t5, o2); ins5b(t5, o3); ins5b(t5, o4);
  }
  if (lane == 0) {
    float sum = t5[0] * t5[0] + t5[1] * t5[1] + t5[2] * t5[2] + t5[3] * t5[3] + t5[4] * t5[4];
    float dens = expf(-(sum / 5.0f)) + jax_uniform_bn(b * N + i) * 1e-6f;
    density[b * N + i] = dens;
    rowmax[b * N + i] = mx;
  }
}

// ---------------- distmax[b] = max over rowmax[b,:] ----------------
__global__ __launch_bounds__(1024) void k_dmax(const float* __restrict__ rowmax,
                                               float* __restrict__ distmax) {
  __shared__ float red[16];
  int b = blockIdx.x;
  int tid = threadIdx.x;
  const float* rb = rowmax + (size_t)b * N;
  float mx = 0.f;
  for (int j = tid; j < N; j += 1024) mx = fmaxf(mx, rb[j]);
#pragma unroll
  for (int m = 1; m < 64; m <<= 1) mx = fmaxf(mx, __shfl_xor(mx, m, 64));
  if ((tid & 63) == 0) red[tid >> 6] = mx;
  __syncthreads();
  if (tid == 0) {
    float r = red[0];
#pragma unroll
    for (int q = 1; q < 16; ++q) r = fmaxf(r, red[q]);
    distmax[b] = r;
  }
}

// ---------------- masked min -> score: one wave per row, shared density stage ----------------
__global__ __launch_bounds__(256) void k_maskmin(const float* __restrict__ distbuf,
                                                 const float* __restrict__ density,
                                                 const float* __restrict__ distmax,
                                                 float* __restrict__ score, int b0) {
  __shared__ float sd[N];
  int tid = threadIdx.x;
  int wv = tid >> 6, lane = tid & 63;
  int i = blockIdx.x * 4 + wv;
  int bl = blockIdx.y, b = b0 + bl;
  const float* db = density + (size_t)b * N;
  for (int j = tid * 4; j < N; j += 1024) *(float4*)(sd + j) = *(const float4*)(db + j);
  __syncthreads();
  float di = sd[i];
  float dmax = distmax[b];
  const float* row = distbuf + ((size_t)bl * N + i) * N;
  float mn = dmax;
#pragma unroll
  for (int it = 0; it < N / 256; ++it) {
    int j = it * 256 + lane * 4;
    float4 v = *(const float4*)(row + j);
    float4 d = *(const float4*)(sd + j);
    mn = fminf(mn, (d.x > di) ? v.x : dmax);
    mn = fminf(mn, (d.y > di) ? v.y : dmax);
    mn = fminf(mn, (d.z > di) ? v.z : dmax);
    mn = fminf(mn, (d.w > di) ? v.w : dmax);
  }
#pragma unroll
  for (int m = 1; m < 64; m <<= 1) mn = fminf(mn, __shfl_xor(mn, m, 64));
  if (lane == 0) score[b * N + i] = mn * di;
}

// ---------------- counting-rank top-CL ----------------
__global__ __launch_bounds__(256) void k_rank(const float* __restrict__ score,
                                              int* __restrict__ index_down,
                                              int* __restrict__ rank, int b0) {
  __shared__ float ssc[N];
  int tid = threadIdx.x;
  int wv = tid >> 6, lane = tid & 63;
  int i = blockIdx.x * 4 + wv;
  int b = b0 + blockIdx.y;
  const float* sb = score + (size_t)b * N;
  for (int j = tid * 4; j < N; j += 1024) *(float4*)(ssc + j) = *(const float4*)(sb + j);
  __syncthreads();
  float si = ssc[i];
  int cnt = 0;
#pragma unroll
  for (int it = 0; it < N / 256; ++it) {
    int j = it * 256 + lane * 4;
    float4 v = *(const float4*)(ssc + j);
    cnt += (v.x > si) || (v.x == si && (j + 0) < i);
    cnt += (v.y > si) || (v.y == si && (j + 1) < i);
    cnt += (v.z > si) || (v.z == si && (j + 2) < i);
    cnt += (v.w > si) || (v.w == si && (j + 3) < i);
  }
#pragma unroll
  for (int m = 1; m < 64; m <<= 1) cnt += __shfl_xor(cnt, m, 64);
  if (lane == 0) {
    rank[b * N + i] = (cnt < CL) ? cnt : -1;
    if (cnt < CL) index_down[b * CL + cnt] = i;
  }
}

// ---------------- assignment ----------------
__global__ __launch_bounds__(256) void k_assign_part(const float* __restrict__ distbuf,
                                                     const int* __restrict__ index_down,
                                                     unsigned long long* __restrict__ packed, int b0) {
  constexpr int RCH = CL / 8;  // 96
  __shared__ int sid[RCH];
  int bl = blockIdx.z, b = b0 + bl;
  int r0 = blockIdx.y * RCH;
  int tid = threadIdx.x;
  for (int r = tid; r < RCH; r += 256) sid[r] = index_down[b * CL + r0 + r];
  __syncthreads();
  int j = blockIdx.x * 256 + tid;
  const float* base = distbuf + (size_t)bl * N * N;
  float best = FLT_MAX; int bestr = 0;
#pragma unroll 8
  for (int r = 0; r < RCH; ++r) {
    float d = base[(size_t)sid[r] * N + j];
    if (d < best) { best = d; bestr = r0 + r; }
  }
  unsigned long long key = ((unsigned long long)__float_as_uint(best) << 32) | (unsigned)bestr;
  atomicMin(&packed[b * N + j], key);
}

__global__ void k_assign_fin2(const unsigned long long* __restrict__ packed,
                              const int* __restrict__ rank,
                              int* __restrict__ idx_cluster, int* __restrict__ counts) {
  int g = blockIdx.x * 256 + threadIdx.x;
  int b = g / N;
  int r = rank[g];
  int cl = (r >= 0) ? r : (int)(unsigned)(packed[g] & 0xffffffffull);
  idx_cluster[g] = cl;
  atomicAdd(&counts[b * CL + cl], 1);
}

// ---------------- merge ----------------
__global__ __launch_bounds__(1024) void k_scan(const int* __restrict__ counts,
                                               int* __restrict__ offsets, int* __restrict__ cursor) {
  constexpr int T = B * CL;
  __shared__ int sm[T];
  int tid = threadIdx.x;
  for (int p = tid; p < T; p += 1024) sm[p] = counts[p];
  __syncthreads();
  for (int off = 1; off < T; off <<= 1) {
    int v[3]; int n = 0;
    for (int p = tid; p < T; p += 1024) { v[n++] = (p >= off) ? sm[p - off] : 0; }
    __syncthreads();
    n = 0;
    for (int p = tid; p < T; p += 1024) { sm[p] += v[n++]; }
    __syncthreads();
  }
  for (int p = tid; p < T; p += 1024) {
    int e = sm[p] - counts[p];
    offsets[p] = e; cursor[p] = e;
  }
}

__global__ void k_fill(const int* __restrict__ idx_cluster, int* __restrict__ cursor,
                       int* __restrict__ members) {
  int g = blockIdx.x * 256 + threadIdx.x;
  int b = g / N, i = g % N;
  int seg = b * CL + idx_cluster[g];
  int pos = atomicAdd(&cursor[seg], 1);
  members[pos] = i;
}

__global__ __launch_bounds__(128) void k_gather(const float* __restrict__ x, const int* __restrict__ members,
                                                const int* __restrict__ offsets, const int* __restrict__ counts,
                                                float* __restrict__ out0) {
  int seg = blockIdx.x;
  int b = seg / CL;
  int cnt = counts[seg], off = offsets[seg];
  float nw = 1.0f / ((float)cnt + 1e-6f);
  int c = threadIdx.x * 4;
  const float* xb = x + (size_t)b * N * C;
  float4 acc = make_float4(0.f, 0.f, 0.f, 0.f);
  for (int m = 0; m < cnt; ++m) {
    int tok = members[off + m];
    float4 v = *(const float4*)(xb + (size_t)tok * C + c);
    acc.x += v.x * nw; acc.y += v.y * nw; acc.z += v.z * nw; acc.w += v.w * nw;
  }
  *(float4*)(out0 + (size_t)seg * C + c) = acc;
}

__global__ void k_final(const float* __restrict__ agg_weight, const int* __restrict__ idx_token,
                        const int* __restrict__ idx_cluster, const int* __restrict__ counts,
                        float* __restrict__ out1, float* __restrict__ out2, float* __restrict__ out3) {
  int g = blockIdx.x * 256 + threadIdx.x;
  int b = g / N;
  int it = idx_token[g];
  int clt = idx_cluster[b * N + it];
  float nwt = 1.0f / ((float)counts[b * CL + clt] + 1e-6f);
  out1[g] = agg_weight[g] * nwt;
  out2[g] = (float)clt;
  out3[g] = (float)idx_cluster[g];
}

// ---------------- launch ----------------
extern "C" void kernel_launch(void* const* d_in, const int* in_sizes, int n_in,
                              void* d_out, int out_size, void* d_ws, size_t ws_size,
                              hipStream_t stream) {
  const float* x          = (const float*)d_in[0];
  const int*   idx_token  = (const int*)d_in[1];
  const float* agg_weight = (const float*)d_in[2];

  float* out0 = (float*)d_out;
  float* out1 = out0 + (size_t)B * CL * C;
  float* out2 = out1 + (size_t)B * N;
  float* out3 = out2 + (size_t)B * N;

  char* w = (char*)d_ws;
  auto carve = [&](size_t bytes) { char* p = w; w += (bytes + 255) & ~(size_t)255; return p; };
  float*    sq         = (float*)carve((size_t)B * N * 4);
  float*    density    = (float*)carve((size_t)B * N * 4);
  float*    score      = (float*)carve((size_t)B * N * 4);
  float*    rowmax     = (float*)carve((size_t)B * N * 4);
  float*    distmax    = (float*)carve((size_t)B * 4);
  int*      index_down = (int*)carve((size_t)B * CL * 4);
  int*      rank       = (int*)carve((size_t)B * N * 4);
  int*      idx_clus   = (int*)carve((size_t)B * N * 4);
  int*      counts     = (int*)carve((size_t)B * CL * 4);
  int*      offsets    = (int*)carve((size_t)B * CL * 4);
  int*      cursor     = (int*)carve((size_t)B * CL * 4);
  int*      members    = (int*)carve((size_t)B * N * 4);
  unsigned long long* packed = (unsigned long long*)carve((size_t)B * N * 8);
  u16*      xhi        = (u16*)carve((size_t)B * N * C * 2);
  u16*      xlo        = (u16*)carve((size_t)B * N * C * 2);
  size_t used = (size_t)(w - (char*)d_ws);
  size_t per  = (size_t)N * N * 4;
  int nb_max = (ws_size > used) ? (int)((ws_size - used) / per) : 0;
  if (nb_max < 1) nb_max = 1;
  if (nb_max > B) nb_max = B;
  float* distbuf = (float*)w;

  k_init<<<(B * N) / 256, 256, 0, stream>>>(counts, packed);
  k_sq<<<B * N, 64, 0, stream>>>(x, sq);
  k_split<<<(B * N * C) / 1024, 256, 0, stream>>>(x, xhi, xlo);

  for (int b0 = 0; b0 < B; b0 += nb_max) {
    int nb = (B - b0 < nb_max) ? (B - b0) : nb_max;
    k_distm<<<dim3(NTILE3, nb), 256, 0, stream>>>(xhi, xlo, sq, distbuf, b0);
    k_knn<<<dim3(N / 4, nb), 256, 0, stream>>>(distbuf, density, rowmax, b0);
    k_dmax<<<nb, 1024, 0, stream>>>(rowmax + (size_t)b0 * N, distmax + b0);
    k_maskmin<<<dim3(N / 4, nb), 256, 0, stream>>>(distbuf, density, distmax, score, b0);
    k_rank<<<dim3(N / 4, nb), 256, 0, stream>>>(score, index_down, rank, b0);
    k_assign_part<<<dim3(N / 256, 8, nb), 256, 0, stream>>>(distbuf, index_down, packed, b0);
  }

  k_assign_fin2<<<(B * N) / 256, 256, 0, stream>>>(packed, rank, idx_clus, counts);
  k_scan<<<1, 1024, 0, stream>>>(counts, offsets, cursor);
  k_fill<<<(B * N) / 256, 256, 0, stream>>>(idx_clus, cursor, members);
  k_gather<<<B * CL, 128, 0, stream>>>(x, members, offsets, counts, out0);
  k_final<<<(B * N) / 256, 256, 0, stream>>>(agg_weight, idx_token, idx_clus, counts, out1, out2, out3);
}

// Round 11
// 307.141 us; speedup vs baseline: 3.9240x; 1.0048x over previous
//
#include <hip/hip_runtime.h>
#include <math.h>
#include <float.h>

constexpr int B  = 4;
constexpr int N  = 3072;
constexpr int C  = 512;
constexpr int CL = 768;

typedef unsigned short u16;
typedef __attribute__((ext_vector_type(8))) short s16x8;
typedef __attribute__((ext_vector_type(4))) float f32x4;

// ---------------- JAX threefry2x32 (exact) ----------------
__device__ __forceinline__ unsigned rotl32(unsigned v, int d) { return (v << d) | (v >> (32 - d)); }

__device__ inline void threefry2x32(unsigned k0, unsigned k1, unsigned c0, unsigned c1,
                                    unsigned& o0, unsigned& o1) {
  unsigned ks0 = k0, ks1 = k1, ks2 = 0x1BD11BDAu ^ k0 ^ k1;
  unsigned x0 = c0 + ks0, x1 = c1 + ks1;
#define TF_RND(r) { x0 += x1; x1 = rotl32(x1, (r)); x1 ^= x0; }
  TF_RND(13) TF_RND(15) TF_RND(26) TF_RND(6)  x0 += ks1; x1 += ks2 + 1u;
  TF_RND(17) TF_RND(29) TF_RND(16) TF_RND(24) x0 += ks2; x1 += ks0 + 2u;
  TF_RND(13) TF_RND(15) TF_RND(26) TF_RND(6)  x0 += ks0; x1 += ks1 + 3u;
  TF_RND(17) TF_RND(29) TF_RND(16) TF_RND(24) x0 += ks1; x1 += ks2 + 4u;
  TF_RND(13) TF_RND(15) TF_RND(26) TF_RND(6)  x0 += ks2; x1 += ks0 + 5u;
#undef TF_RND
  o0 = x0; o1 = x1;
}

__device__ inline float jax_uniform_bn(int f) {
  constexpr int HALF = (B * N) / 2;
  unsigned o0, o1, bits;
  if (f < HALF) { threefry2x32(0u, 42u, (unsigned)f, (unsigned)(f + HALF), o0, o1); bits = o0; }
  else          { threefry2x32(0u, 42u, (unsigned)(f - HALF), (unsigned)f, o0, o1); bits = o1; }
  return __uint_as_float((bits >> 9) | 0x3f800000u) - 1.0f;
}

// ---------------- init ----------------
__global__ void k_init(int* counts, unsigned long long* packed) {
  int g = blockIdx.x * 256 + threadIdx.x;
  packed[g] = ~0ull;
  if (g < B * CL) counts[g] = 0;
}

__global__ __launch_bounds__(64) void k_sq(const float* __restrict__ x, float* __restrict__ sq) {
  int row = blockIdx.x;
  int lane = threadIdx.x;
  const float* xr = x + (size_t)row * C;
  float s = 0.f;
  for (int c = lane * 4; c < C; c += 256) {
    float4 v = *(const float4*)(xr + c);
    s += v.x * v.x + v.y * v.y + v.z * v.z + v.w * v.w;
  }
  for (int o = 32; o > 0; o >>= 1) s += __shfl_down(s, o, 64);
  if (lane == 0) sq[row] = s;
}

// ---------------- split x into bf16 hi/lo ----------------
__device__ __forceinline__ u16 bf16rn(float f) {
  unsigned u = __float_as_uint(f);
  unsigned r = u + 0x7FFFu + ((u >> 16) & 1u);
  return (u16)(r >> 16);
}
__device__ __forceinline__ float bf16tof(u16 h) {
  return __uint_as_float(((unsigned)h) << 16);
}

__global__ void k_split(const float* __restrict__ x, u16* __restrict__ xhi, u16* __restrict__ xlo) {
  int g = (blockIdx.x * 256 + threadIdx.x) * 4;
  float4 v = *(const float4*)(x + g);
  u16 h0 = bf16rn(v.x), h1 = bf16rn(v.y), h2 = bf16rn(v.z), h3 = bf16rn(v.w);
  u16 l0 = bf16rn(v.x - bf16tof(h0));
  u16 l1 = bf16rn(v.y - bf16tof(h1));
  u16 l2 = bf16rn(v.z - bf16tof(h2));
  u16 l3 = bf16rn(v.w - bf16tof(h3));
  uint2 hp, lp;
  hp.x = (unsigned)h0 | ((unsigned)h1 << 16); hp.y = (unsigned)h2 | ((unsigned)h3 << 16);
  lp.x = (unsigned)l0 | ((unsigned)l1 << 16); lp.y = (unsigned)l2 | ((unsigned)l3 << 16);
  *(uint2*)(xhi + g) = hp;
  *(uint2*)(xlo + g) = lp;
}

// ---------------- branchless sorted-insert of v into ascending t[0..4] ----------------
__device__ __forceinline__ void ins5b(float t[5], float v) {
  float c = v;
  float n;
  n = fminf(t[0], c); c = fmaxf(t[0], c); t[0] = n;
  n = fminf(t[1], c); c = fmaxf(t[1], c); t[1] = n;
  n = fminf(t[2], c); c = fmaxf(t[2], c); t[2] = n;
  n = fminf(t[3], c); c = fmaxf(t[3], c); t[3] = n;
  t[4] = fminf(t[4], c);
}

// ---------------- dist via bf16 MFMA (3-term split), 128x128 tile ----------------
// Epilogue additionally emits per-(row, 64-col-slot) 5-NN partials + max into
// part5[bl][slot(48)][q(6)][N]  (q0..4 = sorted top-5 asc, q5 = max).
constexpr int NT3 = N / 128;                   // 24
constexpr int NTILE3 = NT3 * (NT3 + 1) / 2;    // 300

__global__ __launch_bounds__(256) void k_distm(const u16* __restrict__ xhi, const u16* __restrict__ xlo,
                                               const float* __restrict__ sq,
                                               float* __restrict__ distbuf,
                                               float* __restrict__ part5, int b0) {
  constexpr int ASTR = 40;
  __shared__ __align__(16) char smem[40960];
  u16* sAh = (u16*)smem;
  u16* sAl = sAh + 128 * ASTR;
  u16* sBh = sAl + 128 * ASTR;
  u16* sBl = sBh + 128 * ASTR;

  int bl = blockIdx.y, b = b0 + bl;
  int idx = blockIdx.x;
  int ti = 0, rem = idx;
  while (rem >= NT3 - ti) { rem -= NT3 - ti; ++ti; }
  int tj = ti + rem;
  int i0 = ti * 128, j0 = tj * 128;
  bool do_mirror = (ti != tj);

  const float* sqb = sq + (size_t)b * N;
  float* dist = distbuf + (size_t)bl * N * N;

  int tid = threadIdx.x;
  int srow = tid >> 1, shalf = (tid & 1) * 16;
  const u16* gAh = xhi + ((size_t)b * N + i0 + srow) * C + shalf;
  const u16* gAl = xlo + ((size_t)b * N + i0 + srow) * C + shalf;
  const u16* gBh = xhi + ((size_t)b * N + j0 + srow) * C + shalf;
  const u16* gBl = xlo + ((size_t)b * N + j0 + srow) * C + shalf;
  int wofs = srow * ASTR + shalf;

  int lane = tid & 63, w = tid >> 6;
  int wr = (w >> 1) * 64, wc = (w & 1) * 64;
  int l15 = lane & 15, l4 = lane >> 4;

  f32x4 acc[4][4];
#pragma unroll
  for (int rt = 0; rt < 4; ++rt)
#pragma unroll
    for (int ct = 0; ct < 4; ++ct)
#pragma unroll
      for (int e = 0; e < 4; ++e) acc[rt][ct][e] = 0.f;

  uint4 p0 = *(const uint4*)gAh, p1 = *(const uint4*)(gAh + 8);
  uint4 p2 = *(const uint4*)gAl, p3 = *(const uint4*)(gAl + 8);
  uint4 p4 = *(const uint4*)gBh, p5 = *(const uint4*)(gBh + 8);
  uint4 p6 = *(const uint4*)gBl, p7 = *(const uint4*)(gBl + 8);

  for (int k0 = 0; k0 < C; k0 += 32) {
    *(uint4*)&sAh[wofs] = p0; *(uint4*)&sAh[wofs + 8] = p1;
    *(uint4*)&sAl[wofs] = p2; *(uint4*)&sAl[wofs + 8] = p3;
    *(uint4*)&sBh[wofs] = p4; *(uint4*)&sBh[wofs + 8] = p5;
    *(uint4*)&sBl[wofs] = p6; *(uint4*)&sBl[wofs + 8] = p7;
    __syncthreads();
    int kn = k0 + 32;
    if (kn < C) {
      p0 = *(const uint4*)(gAh + kn); p1 = *(const uint4*)(gAh + kn + 8);
      p2 = *(const uint4*)(gAl + kn); p3 = *(const uint4*)(gAl + kn + 8);
      p4 = *(const uint4*)(gBh + kn); p5 = *(const uint4*)(gBh + kn + 8);
      p6 = *(const uint4*)(gBl + kn); p7 = *(const uint4*)(gBl + kn + 8);
    }
    s16x8 ah[4], al[4];
#pragma unroll
    for (int rt = 0; rt < 4; ++rt) {
      int ro = (wr + rt * 16 + l15) * ASTR + l4 * 8;
      ah[rt] = *(const s16x8*)&sAh[ro];
      al[rt] = *(const s16x8*)&sAl[ro];
    }
#pragma unroll
    for (int ct = 0; ct < 4; ++ct) {
      int co = (wc + ct * 16 + l15) * ASTR + l4 * 8;
      s16x8 bh = *(const s16x8*)&sBh[co];
      s16x8 bl = *(const s16x8*)&sBl[co];
#pragma unroll
      for (int rt = 0; rt < 4; ++rt) {
        acc[rt][ct] = __builtin_amdgcn_mfma_f32_16x16x32_bf16(ah[rt], bh, acc[rt][ct], 0, 0, 0);
        acc[rt][ct] = __builtin_amdgcn_mfma_f32_16x16x32_bf16(ah[rt], bl, acc[rt][ct], 0, 0, 0);
        acc[rt][ct] = __builtin_amdgcn_mfma_f32_16x16x32_bf16(al[rt], bh, acc[rt][ct], 0, 0, 0);
      }
    }
    __syncthreads();   // also guards smem reuse by the epilogue below
  }

  const float SQC = 22.627416997969522f;
  float sqi[4][4], sqj[4];
#pragma unroll
  for (int rt = 0; rt < 4; ++rt)
#pragma unroll
    for (int r = 0; r < 4; ++r) sqi[rt][r] = sqb[i0 + wr + rt * 16 + l4 * 4 + r];
#pragma unroll
  for (int ct = 0; ct < 4; ++ct) sqj[ct] = sqb[j0 + wc + ct * 16 + l15];

#pragma unroll
  for (int rt = 0; rt < 4; ++rt)
#pragma unroll
    for (int ct = 0; ct < 4; ++ct)
#pragma unroll
      for (int r = 0; r < 4; ++r) {
        float d2 = fmaxf(sqi[rt][r] + sqj[ct] - 2.0f * acc[rt][ct][r], 0.0f);
        acc[rt][ct][r] = sqrtf(d2) / SQC;
      }

  // ---- epilogue: per-wave LDS transpose (32-col passes):
  //  (a) coalesced float4 direct + mirror writes
  //  (b) per-row 5-NN partials (A-side rows over this wave's 64-col slot;
  //      mirror rows over their 64-col slot)
  constexpr int TSTR = 76;
  float* sT = (float*)smem + w * (32 * TSTR);

  float t5A[5] = {FLT_MAX, FLT_MAX, FLT_MAX, FLT_MAX, FLT_MAX};
  float mxA = 0.f;

#pragma unroll
  for (int p = 0; p < 2; ++p) {
    // stage: cols ct=2p,2p+1 -> sT[cl][rl]
#pragma unroll
    for (int cth = 0; cth < 2; ++cth) {
      int ct = p * 2 + cth;
      int cl = cth * 16 + l15;
#pragma unroll
      for (int rt = 0; rt < 4; ++rt)
#pragma unroll
        for (int r = 0; r < 4; ++r)
          sT[cl * TSTR + rt * 16 + l4 * 4 + r] = acc[rt][ct][r];
    }
    // direct write
    {
      int g4 = lane & 7, rbase = lane >> 3;
#pragma unroll
      for (int it = 0; it < 8; ++it) {
        int rl = it * 8 + rbase;
        float4 v = make_float4(sT[(4 * g4 + 0) * TSTR + rl],
                               sT[(4 * g4 + 1) * TSTR + rl],
                               sT[(4 * g4 + 2) * TSTR + rl],
                               sT[(4 * g4 + 3) * TSTR + rl]);
        *(float4*)(dist + (size_t)(i0 + wr + rl) * N + j0 + wc + p * 32 + 4 * g4) = v;
      }
    }
    // mirror write
    if (do_mirror) {
      int cg = lane >> 4, rq = lane & 15;
#pragma unroll
      for (int cc = 0; cc < 8; ++cc) {
        int c = cc * 4 + cg;
        float4 v = *(const float4*)&sT[c * TSTR + rq * 4];
        *(float4*)(dist + (size_t)(j0 + wc + p * 32 + c) * N + i0 + wr + rq * 4) = v;
      }
    }
    // (b1) A-side partial scan: lane owns row rl=lane, scans this pass's 32 cols
    for (int c = 0; c < 32; ++c) {
      float v = sT[c * TSTR + lane];
      mxA = fmaxf(mxA, v);
      ins5b(t5A, v);
    }
    // (b2) mirror-side partials: 2 lanes per col (halves of 64 rows), then merge
    if (do_mirror) {
      int cl = lane & 31, half = lane >> 5;
      float t5B[5] = {FLT_MAX, FLT_MAX, FLT_MAX, FLT_MAX, FLT_MAX};
      float mxB = 0.f;
      for (int k = 0; k < 32; ++k) {
        float v = sT[cl * TSTR + half * 32 + k];
        mxB = fmaxf(mxB, v);
        ins5b(t5B, v);
      }
      mxB = fmaxf(mxB, __shfl_xor(mxB, 32, 64));
      float o0 = __shfl_xor(t5B[0], 32, 64);
      float o1 = __shfl_xor(t5B[1], 32, 64);
      float o2 = __shfl_xor(t5B[2], 32, 64);
      float o3 = __shfl_xor(t5B[3], 32, 64);
      float o4 = __shfl_xor(t5B[4], 32, 64);
      ins5b(t5B, o0); ins5b(t5B, o1); ins5b(t5B, o2); ins5b(t5B, o3); ins5b(t5B, o4);
      if (half == 0) {
        int rowB = j0 + wc + p * 32 + cl;
        int slotB = ti * 2 + (wr >> 6);
        float* dst = part5 + (((size_t)bl * 48 + slotB) * 6) * N + rowB;
        dst[0] = t5B[0]; dst[(size_t)N] = t5B[1]; dst[2 * (size_t)N] = t5B[2];
        dst[3 * (size_t)N] = t5B[3]; dst[4 * (size_t)N] = t5B[4]; dst[5 * (size_t)N] = mxB;
      }
    }
  }
  // A-side write (64 cols accumulated over both passes)
  {
    int rowA = i0 + wr + lane;
    int slotA = tj * 2 + (wc >> 6);
    float* dst = part5 + (((size_t)bl * 48 + slotA) * 6) * N + rowA;
    dst[0] = t5A[0]; dst[(size_t)N] = t5A[1]; dst[2 * (size_t)N] = t5A[2];
    dst[3 * (size_t)N] = t5A[3]; dst[4 * (size_t)N] = t5A[4]; dst[5 * (size_t)N] = mxA;
  }
}

// ---------------- density from 48-slot partials (replaces full-row k_knn) ----------------
__global__ __launch_bounds__(256) void k_dens(const float* __restrict__ part5,
                                              float* __restrict__ density,
                                              float* __restrict__ rowmax, int b0) {
  int g = blockIdx.x * 256 + threadIdx.x;   // bl*N + r
  int bl = g / N, r = g % N;
  int b = b0 + bl;
  const float* base = part5 + (size_t)bl * 48 * 6 * N + r;
  float t5[5] = {FLT_MAX, FLT_MAX, FLT_MAX, FLT_MAX, FLT_MAX};
  float mx = 0.f;
  for (int s = 0; s < 48; ++s) {
    const float* sp = base + (size_t)s * 6 * N;
    ins5b(t5, sp[0]);
    ins5b(t5, sp[(size_t)N]);
    ins5b(t5, sp[2 * (size_t)N]);
    ins5b(t5, sp[3 * (size_t)N]);
    ins5b(t5, sp[4 * (size_t)N]);
    mx = fmaxf(mx, sp[5 * (size_t)N]);
  }
  float sum = t5[0] * t5[0] + t5[1] * t5[1] + t5[2] * t5[2] + t5[3] * t5[3] + t5[4] * t5[4];
  density[b * N + r] = expf(-(sum / 5.0f)) + jax_uniform_bn(b * N + r) * 1e-6f;
  rowmax[b * N + r] = mx;
}

// ---------------- distmax[b] = max over rowmax[b,:] ----------------
__global__ __launch_bounds__(1024) void k_dmax(const float* __restrict__ rowmax,
                                               float* __restrict__ distmax) {
  __shared__ float red[16];
  int b = blockIdx.x;
  int tid = threadIdx.x;
  const float* rb = rowmax + (size_t)b * N;
  float mx = 0.f;
  for (int j = tid; j < N; j += 1024) mx = fmaxf(mx, rb[j]);
#pragma unroll
  for (int m = 1; m < 64; m <<= 1) mx = fmaxf(mx, __shfl_xor(mx, m, 64));
  if ((tid & 63) == 0) red[tid >> 6] = mx;
  __syncthreads();
  if (tid == 0) {
    float r = red[0];
#pragma unroll
    for (int q = 1; q < 16; ++q) r = fmaxf(r, red[q]);
    distmax[b] = r;
  }
}

// ---------------- masked min -> score: one wave per row, shared density stage ----------------
__global__ __launch_bounds__(256) void k_maskmin(const float* __restrict__ distbuf,
                                                 const float* __restrict__ density,
                                                 const float* __restrict__ distmax,
                                                 float* __restrict__ score, int b0) {
  __shared__ float sd[N];
  int tid = threadIdx.x;
  int wv = tid >> 6, lane = tid & 63;
  int i = blockIdx.x * 4 + wv;
  int bl = blockIdx.y, b = b0 + bl;
  const float* db = density + (size_t)b * N;
  for (int j = tid * 4; j < N; j += 1024) *(float4*)(sd + j) = *(const float4*)(db + j);
  __syncthreads();
  float di = sd[i];
  float dmax = distmax[b];
  const float* row = distbuf + ((size_t)bl * N + i) * N;
  float mn = dmax;
#pragma unroll
  for (int it = 0; it < N / 256; ++it) {
    int j = it * 256 + lane * 4;
    float4 v = *(const float4*)(row + j);
    float4 d = *(const float4*)(sd + j);
    mn = fminf(mn, (d.x > di) ? v.x : dmax);
    mn = fminf(mn, (d.y > di) ? v.y : dmax);
    mn = fminf(mn, (d.z > di) ? v.z : dmax);
    mn = fminf(mn, (d.w > di) ? v.w : dmax);
  }
#pragma unroll
  for (int m = 1; m < 64; m <<= 1) mn = fminf(mn, __shfl_xor(mn, m, 64));
  if (lane == 0) score[b * N + i] = mn * di;
}

// ---------------- counting-rank top-CL ----------------
__global__ __launch_bounds__(256) void k_rank(const float* __restrict__ score,
                                              int* __restrict__ index_down,
                                              int* __restrict__ rank, int b0) {
  __shared__ float ssc[N];
  int tid = threadIdx.x;
  int wv = tid >> 6, lane = tid & 63;
  int i = blockIdx.x * 4 + wv;
  int b = b0 + blockIdx.y;
  const float* sb = score + (size_t)b * N;
  for (int j = tid * 4; j < N; j += 1024) *(float4*)(ssc + j) = *(const float4*)(sb + j);
  __syncthreads();
  float si = ssc[i];
  int cnt = 0;
#pragma unroll
  for (int it = 0; it < N / 256; ++it) {
    int j = it * 256 + lane * 4;
    float4 v = *(const float4*)(ssc + j);
    cnt += (v.x > si) || (v.x == si && (j + 0) < i);
    cnt += (v.y > si) || (v.y == si && (j + 1) < i);
    cnt += (v.z > si) || (v.z == si && (j + 2) < i);
    cnt += (v.w > si) || (v.w == si && (j + 3) < i);
  }
#pragma unroll
  for (int m = 1; m < 64; m <<= 1) cnt += __shfl_xor(cnt, m, 64);
  if (lane == 0) {
    rank[b * N + i] = (cnt < CL) ? cnt : -1;
    if (cnt < CL) index_down[b * CL + cnt] = i;
  }
}

// ---------------- assignment ----------------
__global__ __launch_bounds__(256) void k_assign_part(const float* __restrict__ distbuf,
                                                     const int* __restrict__ index_down,
                                                     unsigned long long* __restrict__ packed, int b0) {
  constexpr int RCH = CL / 8;  // 96
  __shared__ int sid[RCH];
  int bl = blockIdx.z, b = b0 + bl;
  int r0 = blockIdx.y * RCH;
  int tid = threadIdx.x;
  for (int r = tid; r < RCH; r += 256) sid[r] = index_down[b * CL + r0 + r];
  __syncthreads();
  int j = blockIdx.x * 256 + tid;
  const float* base = distbuf + (size_t)bl * N * N;
  float best = FLT_MAX; int bestr = 0;
#pragma unroll 8
  for (int r = 0; r < RCH; ++r) {
    float d = base[(size_t)sid[r] * N + j];
    if (d < best) { best = d; bestr = r0 + r; }
  }
  unsigned long long key = ((unsigned long long)__float_as_uint(best) << 32) | (unsigned)bestr;
  atomicMin(&packed[b * N + j], key);
}

__global__ void k_assign_fin2(const unsigned long long* __restrict__ packed,
                              const int* __restrict__ rank,
                              int* __restrict__ idx_cluster, int* __restrict__ counts) {
  int g = blockIdx.x * 256 + threadIdx.x;
  int b = g / N;
  int r = rank[g];
  int cl = (r >= 0) ? r : (int)(unsigned)(packed[g] & 0xffffffffull);
  idx_cluster[g] = cl;
  atomicAdd(&counts[b * CL + cl], 1);
}

// ---------------- merge ----------------
__global__ __launch_bounds__(1024) void k_scan(const int* __restrict__ counts,
                                               int* __restrict__ offsets, int* __restrict__ cursor) {
  constexpr int T = B * CL;
  __shared__ int sm[T];
  int tid = threadIdx.x;
  for (int p = tid; p < T; p += 1024) sm[p] = counts[p];
  __syncthreads();
  for (int off = 1; off < T; off <<= 1) {
    int v[3]; int n = 0;
    for (int p = tid; p < T; p += 1024) { v[n++] = (p >= off) ? sm[p - off] : 0; }
    __syncthreads();
    n = 0;
    for (int p = tid; p < T; p += 1024) { sm[p] += v[n++]; }
    __syncthreads();
  }
  for (int p = tid; p < T; p += 1024) {
    int e = sm[p] - counts[p];
    offsets[p] = e; cursor[p] = e;
  }
}

__global__ void k_fill(const int* __restrict__ idx_cluster, int* __restrict__ cursor,
                       int* __restrict__ members) {
  int g = blockIdx.x * 256 + threadIdx.x;
  int b = g / N, i = g % N;
  int seg = b * CL + idx_cluster[g];
  int pos = atomicAdd(&cursor[seg], 1);
  members[pos] = i;
}

__global__ __launch_bounds__(128) void k_gather(const float* __restrict__ x, const int* __restrict__ members,
                                                const int* __restrict__ offsets, const int* __restrict__ counts,
                                                float* __restrict__ out0) {
  int seg = blockIdx.x;
  int b = seg / CL;
  int cnt = counts[seg], off = offsets[seg];
  float nw = 1.0f / ((float)cnt + 1e-6f);
  int c = threadIdx.x * 4;
  const float* xb = x + (size_t)b * N * C;
  float4 acc = make_float4(0.f, 0.f, 0.f, 0.f);
  for (int m = 0; m < cnt; ++m) {
    int tok = members[off + m];
    float4 v = *(const float4*)(xb + (size_t)tok * C + c);
    acc.x += v.x * nw; acc.y += v.y * nw; acc.z += v.z * nw; acc.w += v.w * nw;
  }
  *(float4*)(out0 + (size_t)seg * C + c) = acc;
}

__global__ void k_final(const float* __restrict__ agg_weight, const int* __restrict__ idx_token,
                        const int* __restrict__ idx_cluster, const int* __restrict__ counts,
                        float* __restrict__ out1, float* __restrict__ out2, float* __restrict__ out3) {
  int g = blockIdx.x * 256 + threadIdx.x;
  int b = g / N;
  int it = idx_token[g];
  int clt = idx_cluster[b * N + it];
  float nwt = 1.0f / ((float)counts[b * CL + clt] + 1e-6f);
  out1[g] = agg_weight[g] * nwt;
  out2[g] = (float)clt;
  out3[g] = (float)idx_cluster[g];
}

// ---------------- launch ----------------
extern "C" void kernel_launch(void* const* d_in, const int* in_sizes, int n_in,
                              void* d_out, int out_size, void* d_ws, size_t ws_size,
                              hipStream_t stream) {
  const float* x          = (const float*)d_in[0];
  const int*   idx_token  = (const int*)d_in[1];
  const float* agg_weight = (const float*)d_in[2];

  float* out0 = (float*)d_out;
  float* out1 = out0 + (size_t)B * CL * C;
  float* out2 = out1 + (size_t)B * N;
  float* out3 = out2 + (size_t)B * N;

  char* w = (char*)d_ws;
  auto carve = [&](size_t bytes) { char* p = w; w += (bytes + 255) & ~(size_t)255; return p; };
  float*    sq         = (float*)carve((size_t)B * N * 4);
  float*    density    = (float*)carve((size_t)B * N * 4);
  float*    score      = (float*)carve((size_t)B * N * 4);
  float*    rowmax     = (float*)carve((size_t)B * N * 4);
  float*    distmax    = (float*)carve((size_t)B * 4);
  int*      index_down = (int*)carve((size_t)B * CL * 4);
  int*      rank       = (int*)carve((size_t)B * N * 4);
  int*      idx_clus   = (int*)carve((size_t)B * N * 4);
  int*      counts     = (int*)carve((size_t)B * CL * 4);
  int*      offsets    = (int*)carve((size_t)B * CL * 4);
  int*      cursor     = (int*)carve((size_t)B * CL * 4);
  int*      members    = (int*)carve((size_t)B * N * 4);
  unsigned long long* packed = (unsigned long long*)carve((size_t)B * N * 8);
  u16*      xhi        = (u16*)carve((size_t)B * N * C * 2);
  u16*      xlo        = (u16*)carve((size_t)B * N * C * 2);
  float*    part5      = (float*)carve((size_t)B * 48 * 6 * N * 4);
  size_t used = (size_t)(w - (char*)d_ws);
  size_t per  = (size_t)N * N * 4;
  int nb_max = (ws_size > used) ? (int)((ws_size - used) / per) : 0;
  if (nb_max < 1) nb_max = 1;
  if (nb_max > B) nb_max = B;
  float* distbuf = (float*)w;

  k_init<<<(B * N) / 256, 256, 0, stream>>>(counts, packed);
  k_sq<<<B * N, 64, 0, stream>>>(x, sq);
  k_split<<<(B * N * C) / 1024, 256, 0, stream>>>(x, xhi, xlo);

  for (int b0 = 0; b0 < B; b0 += nb_max) {
    int nb = (B - b0 < nb_max) ? (B - b0) : nb_max;
    k_distm<<<dim3(NTILE3, nb), 256, 0, stream>>>(xhi, xlo, sq, distbuf, part5, b0);
    k_dens<<<(nb * N) / 256, 256, 0, stream>>>(part5, density, rowmax, b0);
    k_dmax<<<nb, 1024, 0, stream>>>(rowmax + (size_t)b0 * N, distmax + b0);
    k_maskmin<<<dim3(N / 4, nb), 256, 0, stream>>>(distbuf, density, distmax, score, b0);
    k_rank<<<dim3(N / 4, nb), 256, 0, stream>>>(score, index_down, rank, b0);
    k_assign_part<<<dim3(N / 256, 8, nb), 256, 0, stream>>>(distbuf, index_down, packed, b0);
  }

  k_assign_fin2<<<(B * N) / 256, 256, 0, stream>>>(packed, rank, idx_clus, counts);
  k_scan<<<1, 1024, 0, stream>>>(counts, offsets, cursor);
  k_fill<<<(B * N) / 256, 256, 0, stream>>>(idx_clus, cursor, members);
  k_gather<<<B * CL, 128, 0, stream>>>(x, members, offsets, counts, out0);
  k_final<<<(B * N) / 256, 256, 0, stream>>>(agg_weight, idx_token, idx_clus, counts, out1, out2, out3);
}